// Round 5
// baseline (1987.686 us; speedup 1.0000x reference)
//
#include <hip/hip_runtime.h>
#include <hip/hip_bf16.h>
#include <math.h>

// ---- problem constants ----
#define DURZ 6
#define DURX 5
#define SEQ 257
#define LZ 1542   // 6*257 zr tokens
#define LX 1285   // 5*257 xa tokens
#define LT 2827   // LZ+LX
#define LTP 2880  // LT rounded up to 64 (plane row pad for aligned KV tiles)
#define DM 512
#define NHEADS 8
#define DH 64
#define HIDDEN 2048

typedef __bf16 bf16x8 __attribute__((ext_vector_type(8)));
typedef __bf16 bf16x4 __attribute__((ext_vector_type(4)));
typedef float f32x4 __attribute__((ext_vector_type(4)));

// ---------------- sentinel fill (diagnostic readout channel) ----------------
__global__ void fill_kernel(float* __restrict__ out, int n, float v) {
    int i = blockIdx.x * blockDim.x + threadIdx.x;
    if (i < n) out[i] = v;
}

// ---------------- embed ----------------
__global__ void embed_kernel(const float* __restrict__ z,
                             const float* __restrict__ frames,
                             const int* __restrict__ actions,
                             const float* __restrict__ W_patch,
                             const float* __restrict__ b_patch,
                             const float* __restrict__ registers,
                             const float* __restrict__ pe,
                             const float* __restrict__ action_emb,
                             float* __restrict__ state) {
    int T = blockIdx.x;
    int tid = threadIdx.x;
    bool is_z = T < LZ;
    int T2 = is_z ? T : T - LZ;
    int f = T2 / SEQ, t = T2 % SEQ;
    if (t < 256) {
        const float* src = is_z ? z : frames;
        int hp = t >> 4, wp = t & 15;
        float pv[12];
#pragma unroll
        for (int c = 0; c < 3; c++)
#pragma unroll
            for (int ph = 0; ph < 2; ph++)
#pragma unroll
                for (int pw = 0; pw < 2; pw++)
                    pv[c * 4 + ph * 2 + pw] =
                        src[((f * 3 + c) * 32 + (hp * 2 + ph)) * 32 + (wp * 2 + pw)];
        for (int d = tid; d < DM; d += 256) {
            float acc = b_patch[d];
#pragma unroll
            for (int j = 0; j < 12; j++) acc += pv[j] * W_patch[j * DM + d];
            acc += pe[t * DM + d];
            state[T * DM + d] = acc;
        }
    } else if (is_z) {
        for (int d = tid; d < DM; d += 256) state[T * DM + d] = registers[d];
    } else {
        int a = actions[f];
        for (int d = tid; d < DM; d += 256) state[T * DM + d] = action_emb[a * DM + d];
    }
}

// ---------------- cond vectors ----------------
__global__ void cond_kernel(const int* __restrict__ ts,
                            const float* __restrict__ time_emb,
                            float* __restrict__ condraw,
                            float* __restrict__ condsilu) {
    int idx = blockIdx.x * blockDim.x + threadIdx.x;
    if (idx >= 7 * 512) return;
    int r = idx >> 9;
    int j = idx & 511;
    int tsr = (r < 6) ? ts[r] : 0;
    float x = time_emb[tsr * 512 + j];
    condraw[idx] = x;
    condsilu[idx] = x / (1.0f + expf(-x));
}

// ---------------- params[i][r][c] ----------------
__global__ void params_kernel(const float* __restrict__ condraw,
                              const float* __restrict__ condsilu,
                              const float* __restrict__ W_mod1,
                              const float* __restrict__ b_mod1,
                              const float* __restrict__ W_mod2,
                              const float* __restrict__ b_mod2,
                              const float* __restrict__ W_g1,
                              const float* __restrict__ b_g1,
                              const float* __restrict__ W_g2,
                              const float* __restrict__ b_g2,
                              float* __restrict__ params) {
    int idx = blockIdx.x * blockDim.x + threadIdx.x;
    if (idx >= 6 * 7 * 3072) return;
    int i = idx / 21504;
    int rem = idx % 21504;
    int r = rem / 3072;
    int c = rem % 3072;
    const float* cv;
    const float* W;
    float bias;
    int ldw;
    if (c < 1024) {
        cv = condsilu + r * 512;
        W = W_mod1 + (size_t)i * 512 * 1024 + c; ldw = 1024;
        bias = b_mod1[i * 1024 + c];
    } else if (c < 2048) {
        int cc = c - 1024;
        cv = condsilu + r * 512;
        W = W_mod2 + (size_t)i * 512 * 1024 + cc; ldw = 1024;
        bias = b_mod2[i * 1024 + cc];
    } else if (c < 2560) {
        int cc = c - 2048;
        cv = condraw + r * 512;
        W = W_g1 + (size_t)i * 512 * 512 + cc; ldw = 512;
        bias = b_g1[i * 512 + cc];
    } else {
        int cc = c - 2560;
        cv = condraw + r * 512;
        W = W_g2 + (size_t)i * 512 * 512 + cc; ldw = 512;
        bias = b_g2[i * 512 + cc];
    }
    float acc = bias;
    for (int j = 0; j < 512; j++) acc += cv[j] * W[(size_t)j * ldw];
    params[idx] = acc;
}

// ---------------- zero plane tails (once; epilogues never touch rows>=LT) ---
__global__ void ztail_kernel(__bf16* __restrict__ Kh, __bf16* __restrict__ Kl,
                             __bf16* __restrict__ Vth, __bf16* __restrict__ Vtl) {
    int idx = blockIdx.x * blockDim.x + threadIdx.x;
    if (idx >= (LTP - LT) * 512) return;
    int r = idx / 512, c = idx % 512;
    Kh[(size_t)(LT + r) * DM + c] = (__bf16)0.0f;
    Kl[(size_t)(LT + r) * DM + c] = (__bf16)0.0f;
    Vth[(size_t)c * LTP + LT + r] = (__bf16)0.0f;
    Vtl[(size_t)c * LTP + LT + r] = (__bf16)0.0f;
}

// ---------------- LN + AdaLN modulate -> pre-split bf16 hi/lo planes --------
template<bool PL>
__global__ __launch_bounds__(256) void lnmod_kernel(const float* __restrict__ xf,
                                                    const __bf16* __restrict__ xh,
                                                    const __bf16* __restrict__ xl,
                                                    __bf16* __restrict__ yh,
                                                    __bf16* __restrict__ yl,
                                                    const float* __restrict__ params,
                                                    int mod_off) {
    int T = blockIdx.x;
    int tid = threadIdx.x;
    int r = (T < LZ) ? (T / SEQ) : 6;
    const float* prow = params + r * 3072 + mod_off;
    size_t base = (size_t)T * DM;
    float v0, v1;
    if constexpr (PL) {
        v0 = (float)xh[base + tid] + (float)xl[base + tid];
        v1 = (float)xh[base + tid + 256] + (float)xl[base + tid + 256];
    } else {
        v0 = xf[base + tid];
        v1 = xf[base + tid + 256];
    }
    float s_ = v0 + v1, q_ = v0 * v0 + v1 * v1;
#pragma unroll
    for (int off = 32; off; off >>= 1) {
        s_ += __shfl_down(s_, off);
        q_ += __shfl_down(q_, off);
    }
    __shared__ float sh[8];
    int wave = tid >> 6, lane = tid & 63;
    if (lane == 0) { sh[wave] = s_; sh[4 + wave] = q_; }
    __syncthreads();
    float sum = sh[0] + sh[1] + sh[2] + sh[3];
    float sq = sh[4] + sh[5] + sh[6] + sh[7];
    float mu = sum * (1.0f / 512.0f);
    float var = sq * (1.0f / 512.0f) - mu * mu;
    float rstd = rsqrtf(var + 1e-5f);
    float y0 = (v0 - mu) * rstd * (1.0f + prow[tid]) + prow[512 + tid];
    float y1 = (v1 - mu) * rstd * (1.0f + prow[tid + 256]) + prow[512 + tid + 256];
    __bf16 h0 = (__bf16)y0, h1 = (__bf16)y1;
    yh[base + tid] = h0;
    yl[base + tid] = (__bf16)(y0 - (float)h0);
    yh[base + tid + 256] = h1;
    yl[base + tid + 256] = (__bf16)(y1 - (float)h1);
}

// ================= split-precision bf16 MFMA GEMM family =====================
#define MFMA3(accv, ah, al, bh, bl)                                            \
    accv = __builtin_amdgcn_mfma_f32_16x16x32_bf16(al, bh, accv, 0, 0, 0);     \
    accv = __builtin_amdgcn_mfma_f32_16x16x32_bf16(ah, bl, accv, 0, 0, 0);     \
    accv = __builtin_amdgcn_mfma_f32_16x16x32_bf16(ah, bh, accv, 0, 0, 0);

// ---- per-layer weight pre-split/transpose/tile -----------------------------
// Wp float-offset regions: q 0 | k 327680 | v 655360 | o 983040 |
//                          glu 1310720 | ff 3932160 | end 5242880 (21 MB)
__global__ __launch_bounds__(256) void wprep_kernel(const float* __restrict__ Wq,
                                                    const float* __restrict__ Wk,
                                                    const float* __restrict__ Wv,
                                                    const float* __restrict__ Wo,
                                                    const float* __restrict__ Wglu,
                                                    const float* __restrict__ Wff,
                                                    float* __restrict__ Wp) {
    __shared__ __align__(16) __bf16 T[2][64][40];
    int id = blockIdx.x, t = threadIdx.x;
    const float* src;
    int N, nsub, kt;
    size_t dstf;
    if (id < 512) {
        int mat = id >> 7, rem = id & 127;
        nsub = rem >> 4; kt = rem & 15; N = 512;
        src = mat == 0 ? Wq : mat == 1 ? Wk : mat == 2 ? Wv : Wo;
        dstf = (size_t)mat * 327680 + (size_t)(nsub * 16 + kt) * 2560;
    } else if (id < 1536) {
        int rem = id - 512;
        nsub = rem >> 4; kt = rem & 15; N = 4096; src = Wglu;
        dstf = 1310720 + (size_t)(nsub * 16 + kt) * 2560;
    } else {
        int rem = id - 1536;
        nsub = rem >> 6; kt = rem & 63; N = 512; src = Wff;
        dstf = 3932160 + (size_t)(nsub * 64 + kt) * 2560;
    }
    int r = t >> 2;
    int cb = (t & 3) * 8;
#pragma unroll
    for (int j = 0; j < 8; ++j) {
        int c = cb + j;
        float x = src[(size_t)(kt * 32 + c) * N + nsub * 64 + r];
        __bf16 h = (__bf16)x;
        T[0][r][c] = h;
        T[1][r][c] = (__bf16)(x - (float)h);
    }
    __syncthreads();
    float4* d = (float4*)(Wp + dstf);
    const float4* s4 = (const float4*)(&T[0][0][0]);
    for (int i2 = t; i2 < 640; i2 += 256) d[i2] = s4[i2];
}

#define M_QKV 0
#define M_GATE1 1
#define M_GLU 2
#define M_GATE2 3

// Uniform GEMM: BM = NI*32, BN = 128 output cols (two 64-col B subtiles;
// GLU: 64 a-cols + 64 paired g-cols), BK=32, 4 waves (2M x 2N).
// A fragments load DIRECT from global planes (no LDS, no A staging):
// lane's frag = 16B at row(m0+wm+i*16+lr), col kt*32+q*8 — bit-identical to
// the LDS path. A(kt+1) loaded a full compute-phase early (2-step loop,
// named register sets). B staged via global_load_lds double-buffer,
// issued before current MFMAs so the barrier drain overlaps compute.
template<int MODE, int NI>
__global__ __launch_bounds__(256) void gemm_kernel(
    const __bf16* __restrict__ Aph, const __bf16* __restrict__ Apl,
    const char* __restrict__ Wbase, int KT, int Krow,
    const float* __restrict__ b0, const float* __restrict__ b1,
    const float* __restrict__ b2,
    float* __restrict__ C0,
    __bf16* __restrict__ Oh, __bf16* __restrict__ Ol,
    __bf16* __restrict__ O2h, __bf16* __restrict__ O2l,
    __bf16* __restrict__ O3h, __bf16* __restrict__ O3l,
    const __bf16* __restrict__ Xh, const __bf16* __restrict__ Xl,
    const float* __restrict__ params, int M) {
    constexpr int BM = NI * 32;
    __shared__ __align__(16) __bf16 Blds[2][2][2][64][40];     // buf, sub, plane
    int tid = threadIdx.x;
    int w = tid >> 6, lane = tid & 63;
    int q = lane >> 4, lr = lane & 15;
    // XCD-chunked bijective swizzle (m-fastest within an XCD -> B L2-local)
    int nwg = gridDim.x * gridDim.y;
    int lin = blockIdx.y * gridDim.x + blockIdx.x;
    int qq = nwg >> 3, rr = nwg & 7;
    int xcd = lin & 7, ix = lin >> 3;
    int wg = (xcd < rr) ? xcd * (qq + 1) + ix : rr * (qq + 1) + (xcd - rr) * qq + ix;
    int mb = wg % gridDim.x;
    int nb = wg / gridDim.x;
    int m0 = mb * BM;
    const char* sb0;
    const char* sb1;
    if constexpr (MODE == M_QKV) {
        int sel = nb >> 2;
        const char* mbp = Wbase + (size_t)sel * 1310720;
        sb0 = mbp + (size_t)(2 * (nb & 3)) * 163840;
        sb1 = mbp + (size_t)(2 * (nb & 3) + 1) * 163840;
    } else if constexpr (MODE == M_GLU) {
        sb0 = Wbase + (size_t)nb * 163840;              // a-cols subtile
        sb1 = Wbase + (size_t)(32 + nb) * 163840;       // g-cols subtile
    } else {
        sb0 = Wbase + (size_t)(2 * nb) * (size_t)KT * 10240;
        sb1 = Wbase + (size_t)(2 * nb + 1) * (size_t)KT * 10240;
    }
    int wm = (w >> 1) * (BM / 2);

    // per-thread A row base pointers (clamped m-tail; outputs guarded later)
    const __bf16* aRowH[NI];
    const __bf16* aRowL[NI];
#pragma unroll
    for (int i = 0; i < NI; ++i) {
        int mrow = m0 + wm + i * 16 + lr;
        if (mrow > M - 1) mrow = M - 1;
        aRowH[i] = Aph + (size_t)mrow * Krow + q * 8;
        aRowL[i] = Apl + (size_t)mrow * Krow + q * 8;
    }

    auto stageB = [&](int sbuf, int kt) {
        const char* k0 = sb0 + (size_t)kt * 10240;
        const char* k1 = sb1 + (size_t)kt * 10240;
        char* bl = (char*)(&Blds[sbuf][0][0][0][0]);
        for (int idx = w; idx < 20; idx += 4) {
            int sub = idx & 1, c = idx >> 1;
            const char* g = (sub ? k1 : k0) + (c << 10) + (lane << 4);
            __builtin_amdgcn_global_load_lds((const unsigned int*)g,
                (unsigned int*)(bl + sub * 10240 + (c << 10)), 16, 0, 0);
        }
    };
    auto aloadF = [&](int kt, bf16x8 (&ah)[NI], bf16x8 (&al)[NI]) {
        int off = kt * 32;
#pragma unroll
        for (int i = 0; i < NI; ++i) {
            ah[i] = *(const bf16x8*)(aRowH[i] + off);
            al[i] = *(const bf16x8*)(aRowL[i] + off);
        }
    };

    f32x4 acc[NI][4];
#pragma unroll
    for (int i = 0; i < NI; ++i)
#pragma unroll
        for (int j = 0; j < 4; ++j)
#pragma unroll
            for (int r = 0; r < 4; ++r) acc[i][j][r] = 0.0f;

    auto compute = [&](int buf, bf16x8 (&ah)[NI], bf16x8 (&al)[NI]) {
        bf16x8 bh[4], bl4[4];
#pragma unroll
        for (int j = 0; j < 4; ++j) {
            int bsub, brow;
            if constexpr (MODE == M_GLU) {
                bsub = j >> 1;
                brow = (w & 1) * 32 + (j & 1) * 16 + lr;
            } else {
                bsub = w & 1;
                brow = j * 16 + lr;
            }
            bh[j] = *(const bf16x8*)(&Blds[buf][bsub][0][brow][q * 8]);
            bl4[j] = *(const bf16x8*)(&Blds[buf][bsub][1][brow][q * 8]);
        }
#pragma unroll
        for (int i = 0; i < NI; ++i)
#pragma unroll
            for (int j = 0; j < 4; ++j) {
                MFMA3(acc[i][j], ah[i], al[i], bh[j], bl4[j]);
            }
    };

    bf16x8 A0h[NI], A0l[NI], A1h[NI], A1l[NI];
    stageB(0, 0);
    aloadF(0, A0h, A0l);
    __syncthreads();
    for (int kt = 0; kt < KT; kt += 2) {
        stageB(1, kt + 1);
        aloadF(kt + 1, A1h, A1l);
        compute(0, A0h, A0l);
        __syncthreads();
        if (kt + 2 < KT) {
            stageB(0, kt + 2);
            aloadF(kt + 2, A0h, A0l);
        }
        compute(1, A1h, A1l);
        __syncthreads();
    }

    if constexpr (MODE == M_QKV) {
        int sel = nb >> 2;
        int c0 = (nb & 3) * 128 + (w & 1) * 64;
        if (sel == 2) {
            // V^T hi/lo planes: Vt[(n)][token], 8B vector stores over r
#pragma unroll
            for (int i = 0; i < NI; ++i) {
                int mb2 = m0 + wm + i * 16 + q * 4;
#pragma unroll
                for (int j = 0; j < 4; ++j) {
                    int n = c0 + j * 16 + lr;
                    bf16x4 h4, l4;
#pragma unroll
                    for (int r = 0; r < 4; ++r) {
                        float v = acc[i][j][r] + b2[n];
                        __bf16 hh = (__bf16)v;
                        h4[r] = hh;
                        l4[r] = (__bf16)(v - (float)hh);
                    }
                    if (mb2 + 3 < M) {
                        *(bf16x4*)(O3h + (size_t)n * LTP + mb2) = h4;
                        *(bf16x4*)(O3l + (size_t)n * LTP + mb2) = l4;
                    } else {
#pragma unroll
                        for (int r = 0; r < 4; ++r)
                            if (mb2 + r < M) {
                                O3h[(size_t)n * LTP + mb2 + r] = h4[r];
                                O3l[(size_t)n * LTP + mb2 + r] = l4[r];
                            }
                    }
                }
            }
        } else {
            const float* bias = sel == 0 ? b0 : b1;
            __bf16* Dh = sel == 0 ? Oh : O2h;
            __bf16* Dl = sel == 0 ? Ol : O2l;
            float scale = sel == 0 ? 0.125f : 1.0f;   // fold softmax scale into Q
#pragma unroll
            for (int i = 0; i < NI; ++i)
#pragma unroll
                for (int r = 0; r < 4; ++r) {
                    int m = m0 + wm + i * 16 + q * 4 + r;
                    if (m >= M) continue;
#pragma unroll
                    for (int j = 0; j < 4; ++j) {
                        int n = c0 + j * 16 + lr;
                        float v = (acc[i][j][r] + bias[n]) * scale;
                        __bf16 hh = (__bf16)v;
                        Dh[(size_t)m * DM + n] = hh;
                        Dl[(size_t)m * DM + n] = (__bf16)(v - (float)hh);
                    }
                }
        }
        return;
    }

#pragma unroll
    for (int i = 0; i < NI; ++i)
#pragma unroll
        for (int r = 0; r < 4; ++r) {
            int m = m0 + wm + i * 16 + q * 4 + r;
            if (m >= M) continue;
            if constexpr (MODE == M_GATE1) {
                int r6 = (m < LZ) ? (m / SEQ) : 6;
                const float* g1 = params + r6 * 3072 + 2048;
                int c0 = nb * 128 + (w & 1) * 64;
#pragma unroll
                for (int j = 0; j < 4; ++j) {
                    int n = c0 + j * 16 + lr;
                    size_t o = (size_t)m * 512 + n;
                    float x = (float)Xh[o] + (float)Xl[o];
                    float v = x * g1[n] + acc[i][j][r] + b0[n];
                    __bf16 hh = (__bf16)v;
                    Oh[o] = hh;
                    Ol[o] = (__bf16)(v - (float)hh);
                }
            } else if constexpr (MODE == M_GLU) {
#pragma unroll
                for (int j = 0; j < 2; ++j) {
                    int n = nb * 64 + (w & 1) * 32 + j * 16 + lr;
                    float a = acc[i][j][r] + b0[n];
                    float g = acc[i][j + 2][r] + b0[2048 + n];
                    float gel = 0.5f * g * (1.0f + erff(g * 0.70710678118654752f));
                    float v = a * gel;
                    size_t o = (size_t)m * 2048 + n;
                    __bf16 hh = (__bf16)v;
                    Oh[o] = hh;
                    Ol[o] = (__bf16)(v - (float)hh);
                }
            } else {
                int r6 = (m < LZ) ? (m / SEQ) : 6;
                const float* g2 = params + r6 * 3072 + 2560;
                int c0 = nb * 128 + (w & 1) * 64;
#pragma unroll
                for (int j = 0; j < 4; ++j) {
                    int n = c0 + j * 16 + lr;
                    C0[(size_t)m * 512 + n] = (acc[i][j][r] + b0[n]) * g2[n];
                }
            }
        }
}

// ---- flash attention: all operands pre-split bf16 planes -------------------
__global__ __launch_bounds__(256) void fattn_kernel(
    const __bf16* __restrict__ Qph, const __bf16* __restrict__ Qpl,
    const __bf16* __restrict__ Kph, const __bf16* __restrict__ Kpl,
    const __bf16* __restrict__ Vph, const __bf16* __restrict__ Vpl,
    __bf16* __restrict__ Oh, __bf16* __restrict__ Ol) {
    __shared__ __align__(16) __bf16 Ksh[2][64][64];
    __shared__ __align__(16) __bf16 Vsh[2][64][64];
    __shared__ __align__(16) __bf16 Ph[4][16][72], Pl[4][16][72];
    int tid = threadIdx.x;
    int w = tid >> 6, lane = tid & 63;
    int lq = lane & 15, lg = lane >> 4;
    int hoff = blockIdx.z * DH;
    int qbase, base0, len0, base1, len1;
    if (blockIdx.y < 6) {
        int f = blockIdx.y;
        qbase = f * SEQ;
        base0 = f * SEQ; len0 = SEQ;
        int jl = f - 4; if (jl < 0) jl = 0;
        base1 = LZ + jl * SEQ; len1 = (f - jl) * SEQ;
    } else {
        int f = blockIdx.y - 6;
        qbase = LZ + f * SEQ;
        base0 = LZ; len0 = (f + 1) * SEQ;
        base1 = 0; len1 = 0;
    }
    int q0 = blockIdx.x * 64;
    int qvalid = SEQ - q0; if (qvalid > 64) qvalid = 64;

    bf16x8 qfh[2], qfl[2];
    {
        int qr = w * 16 + lq;
        int tok = qbase + q0 + ((qr < qvalid) ? qr : 0);
        const __bf16* qph = Qph + (size_t)tok * DM + hoff + lg * 8;
        const __bf16* qpl = Qpl + (size_t)tok * DM + hoff + lg * 8;
#pragma unroll
        for (int s = 0; s < 2; ++s) {
            qfh[s] = *(const bf16x8*)(qph + s * 32);
            qfl[s] = *(const bf16x8*)(qpl + s * 32);
        }
    }
    f32x4 acc[4];
#pragma unroll
    for (int n = 0; n < 4; ++n)
#pragma unroll
        for (int r = 0; r < 4; ++r) acc[n][r] = 0.0f;
    float m_i = -1e30f, l_i = 0.0f;
    int slot = lane & 7, rsub = lane >> 3;

    for (int rng = 0; rng < 2; ++rng) {
        int base = rng ? base1 : base0;
        int len = rng ? len1 : len0;
        if (len == 0) continue;
        int tend = base + len;
        for (int t = base & ~63; t < tend; t += 64) {
            int lo = base - t; if (lo < 0) lo = 0;
            int hi = tend - t; if (hi > 64) hi = 64;
            __syncthreads();
#pragma unroll
            for (int ii = 0; ii < 4; ++ii) {
                int idx = w + ii * 4;
                int p = idx >> 3, c = idx & 7;
                int row = c * 8 + rsub;
                const __bf16* g = (p ? Kpl : Kph) +
                    (size_t)(t + row) * DM + hoff + (slot ^ (row & 7)) * 8;
                __builtin_amdgcn_global_load_lds((const unsigned int*)g,
                    (unsigned int*)((char*)(&Ksh[p][0][0]) + c * 1024), 16, 0, 0);
            }
#pragma unroll
            for (int ii = 0; ii < 4; ++ii) {
                int idx = w + ii * 4;
                int p = idx >> 3, c = idx & 7;
                int d = c * 8 + rsub;
                const __bf16* g = (p ? Vpl : Vph) +
                    (size_t)(hoff + d) * LTP + t + (slot ^ (d & 7)) * 8;
                __builtin_amdgcn_global_load_lds((const unsigned int*)g,
                    (unsigned int*)((char*)(&Vsh[p][0][0]) + c * 1024), 16, 0, 0);
            }
            __syncthreads();
            f32x4 st[4];
#pragma unroll
            for (int sub = 0; sub < 4; ++sub)
#pragma unroll
                for (int r = 0; r < 4; ++r) st[sub][r] = 0.0f;
#pragma unroll
            for (int sub = 0; sub < 4; ++sub) {
                int row = sub * 16 + lq;
#pragma unroll
                for (int s = 0; s < 2; ++s) {
                    int sl = ((s * 4 + lg) ^ (row & 7)) * 8;
                    bf16x8 kfh = *(const bf16x8*)(&Ksh[0][row][sl]);
                    bf16x8 kfl = *(const bf16x8*)(&Ksh[1][row][sl]);
                    MFMA3(st[sub], kfh, kfl, qfh[s], qfl[s]);
                }
            }
            float p[16];
            float rmax = -1e30f;
#pragma unroll
            for (int sub = 0; sub < 4; ++sub)
#pragma unroll
                for (int r = 0; r < 4; ++r) {
                    int kk = sub * 16 + lg * 4 + r;
                    float sv = (kk >= lo && kk < hi) ? st[sub][r] : -1e30f;
                    p[sub * 4 + r] = sv;
                    rmax = fmaxf(rmax, sv);
                }
            rmax = fmaxf(rmax, __shfl_xor(rmax, 16));
            rmax = fmaxf(rmax, __shfl_xor(rmax, 32));
            float mnew = fmaxf(m_i, rmax);
            float alpha = __expf(m_i - mnew);
            float rsum = 0.0f;
#pragma unroll
            for (int i2 = 0; i2 < 16; ++i2) {
                p[i2] = __expf(p[i2] - mnew);
                rsum += p[i2];
            }
            rsum += __shfl_xor(rsum, 16);
            rsum += __shfl_xor(rsum, 32);
            l_i = l_i * alpha + rsum;
            m_i = mnew;
            float ar[4];
#pragma unroll
            for (int r = 0; r < 4; ++r) ar[r] = __shfl(alpha, lg * 4 + r);
#pragma unroll
            for (int n = 0; n < 4; ++n)
#pragma unroll
                for (int r = 0; r < 4; ++r) acc[n][r] *= ar[r];
#pragma unroll
            for (int sub = 0; sub < 4; ++sub) {
                bf16x4 h4, l4;
#pragma unroll
                for (int r = 0; r < 4; ++r) {
                    float x = p[sub * 4 + r];
                    __bf16 hh = (__bf16)x;
                    h4[r] = hh;
                    l4[r] = (__bf16)(x - (float)hh);
                }
                *(bf16x4*)&Ph[w][lq][sub * 16 + lg * 4] = h4;
                *(bf16x4*)&Pl[w][lq][sub * 16 + lg * 4] = l4;
            }
            bf16x8 pah[2], pal[2];
#pragma unroll
            for (int s = 0; s < 2; ++s) {
                pah[s] = *(const bf16x8*)(&Ph[w][lq][s * 32 + lg * 8]);
                pal[s] = *(const bf16x8*)(&Pl[w][lq][s * 32 + lg * 8]);
            }
#pragma unroll
            for (int n = 0; n < 4; ++n) {
                int row = n * 16 + lq;
#pragma unroll
                for (int s = 0; s < 2; ++s) {
                    int sl = ((s * 4 + lg) ^ (row & 7)) * 8;
                    bf16x8 vfh = *(const bf16x8*)(&Vsh[0][row][sl]);
                    bf16x8 vfl = *(const bf16x8*)(&Vsh[1][row][sl]);
                    MFMA3(acc[n], pah[s], pal[s], vfh, vfl);
                }
            }
        }
    }
    float linv[4];
#pragma unroll
    for (int r = 0; r < 4; ++r) linv[r] = 1.0f / __shfl(l_i, lg * 4 + r);
#pragma unroll
    for (int r = 0; r < 4; ++r) {
        int qr = w * 16 + lg * 4 + r;
        if (qr < qvalid) {
            size_t ob = (size_t)(qbase + q0 + qr) * DM + hoff;
#pragma unroll
            for (int n = 0; n < 4; ++n) {
                float v = acc[n][r] * linv[r];
                __bf16 hh = (__bf16)v;
                Oh[ob + n * 16 + lq] = hh;
                Ol[ob + n * 16 + lq] = (__bf16)(v - (float)hh);
            }
        }
    }
}

// ---------------- unpatch to FP32 output ------------------
__global__ void unpatch_kernel(const float* __restrict__ state,
                               const float* __restrict__ Wu,
                               const float* __restrict__ bu,
                               float* __restrict__ out) {
    int idx = blockIdx.x * blockDim.x + threadIdx.x;
    if (idx >= DURZ * 3 * 32 * 32) return;
    int w = idx & 31, hh = (idx >> 5) & 31, c = (idx >> 10) % 3, f = idx / (3 * 1024);
    int t = (hh >> 1) * 16 + (w >> 1);
    int j = c * 4 + (hh & 1) * 2 + (w & 1);
    const float* xr = state + (size_t)(f * SEQ + t) * DM;
    float acc = bu[j];
    for (int k = 0; k < DM; ++k) acc += xr[k] * Wu[k * 12 + j];
    out[idx] = acc;
}

extern "C" void kernel_launch(void* const* d_in, const int* in_sizes, int n_in,
                              void* d_out, int out_size, void* d_ws, size_t ws_size,
                              hipStream_t stream) {
    static const int expected_sizes[32] = {
        18432, 15360, 6, 6,
        6144, 512, 6144, 12,
        512, 131072, 1536, 512000,
        3145728, 6144, 3145728, 6144,
        1572864, 3072, 1572864, 3072,
        1572864, 3072, 1572864, 3072,
        1572864, 3072, 1572864, 3072,
        12582912, 24576, 6291456, 3072
    };
    if (n_in != 32) {
        fill_kernel<<<(18432 + 255) / 256, 256, 0, stream>>>((float*)d_out, 18432, 3.0f);
        return;
    }
    for (int i = 0; i < 32; ++i) {
        if (in_sizes[i] != expected_sizes[i]) {
            fill_kernel<<<(18432 + 255) / 256, 256, 0, stream>>>((float*)d_out, 18432,
                                                                 4.0f + (float)i);
            return;
        }
    }

    const float* z = (const float*)d_in[0];
    const float* frames = (const float*)d_in[1];
    const int* actions = (const int*)d_in[2];
    const int* ts = (const int*)d_in[3];
    const float* W_patch = (const float*)d_in[4];
    const float* b_patch = (const float*)d_in[5];
    const float* W_unpatch = (const float*)d_in[6];
    const float* b_unpatch = (const float*)d_in[7];
    const float* registers = (const float*)d_in[8];
    const float* pe_grid = (const float*)d_in[9];
    const float* action_emb = (const float*)d_in[10];
    const float* time_emb = (const float*)d_in[11];
    const float* W_mod1 = (const float*)d_in[12];
    const float* b_mod1 = (const float*)d_in[13];
    const float* W_mod2 = (const float*)d_in[14];
    const float* b_mod2 = (const float*)d_in[15];
    const float* W_q = (const float*)d_in[16];
    const float* b_q = (const float*)d_in[17];
    const float* W_k = (const float*)d_in[18];
    const float* b_k = (const float*)d_in[19];
    const float* W_v = (const float*)d_in[20];
    const float* b_v = (const float*)d_in[21];
    const float* W_o = (const float*)d_in[22];
    const float* b_o = (const float*)d_in[23];
    const float* W_g1 = (const float*)d_in[24];
    const float* b_g1 = (const float*)d_in[25];
    const float* W_g2 = (const float*)d_in[26];
    const float* b_g2 = (const float*)d_in[27];
    const float* W_geglu = (const float*)d_in[28];
    const float* b_geglu = (const float*)d_in[29];
    const float* W_ffout = (const float*)d_in[30];
    const float* b_ffout = (const float*)d_in[31];

    const size_t S = (size_t)LT * DM;          // 1,447,424 floats
    const size_t PLE = (size_t)LTP * DM;       // plane bf16 elems = 1,474,560
    const size_t PLF = PLE / 2;                // plane floats = 737,280
    size_t need = (4 * S + 6 * PLF + 129024 + 7168 + 5242880) * sizeof(float);
    if (ws_size < need) {
        fill_kernel<<<(18432 + 255) / 256, 256, 0, stream>>>((float*)d_out, 18432, 40.0f);
        return;
    }
    float* ws = (float*)d_ws;
    float* state = ws;                              // [0, 1S)
    __bf16* xnh = (__bf16*)(ws + S);                // [1S, 1.5S)
    __bf16* xnl = (__bf16*)(ws + S + S / 2);        // [1.5S, 2S)
    __bf16* Qh = (__bf16*)(ws + 2 * S);             // 6 planes of PLE bf16
    __bf16* Ql = Qh + PLE;
    __bf16* Kh = Qh + 2 * PLE;
    __bf16* Kl = Qh + 3 * PLE;
    __bf16* Vth = Qh + 4 * PLE;
    __bf16* Vtl = Qh + 5 * PLE;
    float* aoff = ws + 2 * S + 6 * PLF;
    __bf16* atth = (__bf16*)aoff;                   // S bf16
    __bf16* attl = atth + S;
    __bf16* y2h = (__bf16*)(aoff + S);
    __bf16* y2l = y2h + S;
    __bf16* Hph = (__bf16*)(ws + 2 * S);            // overlay (planes+att dead)
    __bf16* Hpl = Hph + (size_t)LT * HIDDEN;
    float* params = aoff + 2 * S;
    float* condraw = params + 129024;
    float* condsilu = condraw + 3584;
    float* wp = condsilu + 3584;                    // 5,242,880 floats

    embed_kernel<<<LT, 256, 0, stream>>>(z, frames, actions, W_patch, b_patch,
                                         registers, pe_grid, action_emb, state);
    cond_kernel<<<(7 * 512 + 255) / 256, 256, 0, stream>>>(ts, time_emb, condraw, condsilu);
    params_kernel<<<(6 * 7 * 3072 + 255) / 256, 256, 0, stream>>>(
        condraw, condsilu, W_mod1, b_mod1, W_mod2, b_mod2, W_g1, b_g1, W_g2, b_g2, params);
    ztail_kernel<<<((LTP - LT) * 512 + 255) / 256, 256, 0, stream>>>(Kh, Kl, Vth, Vtl);

    dim3 gqkv(45, 12);
    dim3 ggate1(45, 4);
    dim3 gglu(23, 32);
    dim3 ggate2(45, 4);
    dim3 gattn(5, 11, NHEADS);
    for (int i = 0; i < 6; ++i) {
        const float* P = params + i * 21504;
        wprep_kernel<<<2048, 256, 0, stream>>>(
            W_q + (size_t)i * DM * DM, W_k + (size_t)i * DM * DM,
            W_v + (size_t)i * DM * DM, W_o + (size_t)i * DM * DM,
            W_geglu + (size_t)i * DM * 4096, W_ffout + (size_t)i * HIDDEN * DM, wp);
        lnmod_kernel<false><<<LT, 256, 0, stream>>>(state, nullptr, nullptr,
                                                    xnh, xnl, P, 0);
        gemm_kernel<M_QKV, 2><<<gqkv, 256, 0, stream>>>(
            xnh, xnl, (const char*)wp, 16, 512,
            b_q + i * DM, b_k + i * DM, b_v + i * DM, nullptr,
            Qh, Ql, Kh, Kl, Vth, Vtl, nullptr, nullptr, nullptr, LT);
        fattn_kernel<<<gattn, 256, 0, stream>>>(Qh, Ql, Kh, Kl, Vth, Vtl, atth, attl);
        gemm_kernel<M_GATE1, 2><<<ggate1, 256, 0, stream>>>(
            atth, attl, (const char*)(wp + 983040), 16, 512,
            b_o + i * DM, nullptr, nullptr, nullptr,
            y2h, y2l, nullptr, nullptr, nullptr, nullptr, xnh, xnl, P, LT);
        lnmod_kernel<true><<<LT, 256, 0, stream>>>(nullptr, y2h, y2l,
                                                   xnh, xnl, P, 1024);
        gemm_kernel<M_GLU, 4><<<gglu, 256, 0, stream>>>(
            xnh, xnl, (const char*)(wp + 1310720), 16, 512,
            b_geglu + (size_t)i * 4096, nullptr, nullptr, nullptr,
            Hph, Hpl, nullptr, nullptr, nullptr, nullptr, nullptr, nullptr, nullptr, LT);
        gemm_kernel<M_GATE2, 2><<<ggate2, 256, 0, stream>>>(
            Hph, Hpl, (const char*)(wp + 3932160), 64, 2048,
            b_ffout + i * DM, nullptr, nullptr, state,
            nullptr, nullptr, nullptr, nullptr, nullptr, nullptr,
            nullptr, nullptr, P, LT);
    }
    unpatch_kernel<<<(DURZ * 3 * 32 * 32 + 255) / 256, 256, 0, stream>>>(
        state, W_unpatch, b_unpatch, (float*)d_out);
}

// Round 6
// 1770.803 us; speedup vs baseline: 1.1225x; 1.1225x over previous
//
#include <hip/hip_runtime.h>
#include <hip/hip_bf16.h>
#include <math.h>

// ---- problem constants ----
#define DURZ 6
#define DURX 5
#define SEQ 257
#define LZ 1542   // 6*257 zr tokens
#define LX 1285   // 5*257 xa tokens
#define LT 2827   // LZ+LX
#define LTP 2880  // LT rounded up to 64 (plane row pad for aligned KV tiles)
#define DM 512
#define NHEADS 8
#define DH 64
#define HIDDEN 2048

typedef __bf16 bf16x8 __attribute__((ext_vector_type(8)));
typedef __bf16 bf16x4 __attribute__((ext_vector_type(4)));
typedef float f32x4 __attribute__((ext_vector_type(4)));

// ---------------- sentinel fill (diagnostic readout channel) ----------------
__global__ void fill_kernel(float* __restrict__ out, int n, float v) {
    int i = blockIdx.x * blockDim.x + threadIdx.x;
    if (i < n) out[i] = v;
}

// ---------------- embed ----------------
__global__ void embed_kernel(const float* __restrict__ z,
                             const float* __restrict__ frames,
                             const int* __restrict__ actions,
                             const float* __restrict__ W_patch,
                             const float* __restrict__ b_patch,
                             const float* __restrict__ registers,
                             const float* __restrict__ pe,
                             const float* __restrict__ action_emb,
                             float* __restrict__ state) {
    int T = blockIdx.x;
    int tid = threadIdx.x;
    bool is_z = T < LZ;
    int T2 = is_z ? T : T - LZ;
    int f = T2 / SEQ, t = T2 % SEQ;
    if (t < 256) {
        const float* src = is_z ? z : frames;
        int hp = t >> 4, wp = t & 15;
        float pv[12];
#pragma unroll
        for (int c = 0; c < 3; c++)
#pragma unroll
            for (int ph = 0; ph < 2; ph++)
#pragma unroll
                for (int pw = 0; pw < 2; pw++)
                    pv[c * 4 + ph * 2 + pw] =
                        src[((f * 3 + c) * 32 + (hp * 2 + ph)) * 32 + (wp * 2 + pw)];
        for (int d = tid; d < DM; d += 256) {
            float acc = b_patch[d];
#pragma unroll
            for (int j = 0; j < 12; j++) acc += pv[j] * W_patch[j * DM + d];
            acc += pe[t * DM + d];
            state[T * DM + d] = acc;
        }
    } else if (is_z) {
        for (int d = tid; d < DM; d += 256) state[T * DM + d] = registers[d];
    } else {
        int a = actions[f];
        for (int d = tid; d < DM; d += 256) state[T * DM + d] = action_emb[a * DM + d];
    }
}

// ---------------- cond vectors ----------------
__global__ void cond_kernel(const int* __restrict__ ts,
                            const float* __restrict__ time_emb,
                            float* __restrict__ condraw,
                            float* __restrict__ condsilu) {
    int idx = blockIdx.x * blockDim.x + threadIdx.x;
    if (idx >= 7 * 512) return;
    int r = idx >> 9;
    int j = idx & 511;
    int tsr = (r < 6) ? ts[r] : 0;
    float x = time_emb[tsr * 512 + j];
    condraw[idx] = x;
    condsilu[idx] = x / (1.0f + expf(-x));
}

// ---------------- params[i][r][c] ----------------
__global__ void params_kernel(const float* __restrict__ condraw,
                              const float* __restrict__ condsilu,
                              const float* __restrict__ W_mod1,
                              const float* __restrict__ b_mod1,
                              const float* __restrict__ W_mod2,
                              const float* __restrict__ b_mod2,
                              const float* __restrict__ W_g1,
                              const float* __restrict__ b_g1,
                              const float* __restrict__ W_g2,
                              const float* __restrict__ b_g2,
                              float* __restrict__ params) {
    int idx = blockIdx.x * blockDim.x + threadIdx.x;
    if (idx >= 6 * 7 * 3072) return;
    int i = idx / 21504;
    int rem = idx % 21504;
    int r = rem / 3072;
    int c = rem % 3072;
    const float* cv;
    const float* W;
    float bias;
    int ldw;
    if (c < 1024) {
        cv = condsilu + r * 512;
        W = W_mod1 + (size_t)i * 512 * 1024 + c; ldw = 1024;
        bias = b_mod1[i * 1024 + c];
    } else if (c < 2048) {
        int cc = c - 1024;
        cv = condsilu + r * 512;
        W = W_mod2 + (size_t)i * 512 * 1024 + cc; ldw = 1024;
        bias = b_mod2[i * 1024 + cc];
    } else if (c < 2560) {
        int cc = c - 2048;
        cv = condraw + r * 512;
        W = W_g1 + (size_t)i * 512 * 512 + cc; ldw = 512;
        bias = b_g1[i * 512 + cc];
    } else {
        int cc = c - 2560;
        cv = condraw + r * 512;
        W = W_g2 + (size_t)i * 512 * 512 + cc; ldw = 512;
        bias = b_g2[i * 512 + cc];
    }
    float acc = bias;
    for (int j = 0; j < 512; j++) acc += cv[j] * W[(size_t)j * ldw];
    params[idx] = acc;
}

// ---------------- zero plane tails (once; epilogues never touch rows>=LT) ---
__global__ void ztail_kernel(__bf16* __restrict__ Kh, __bf16* __restrict__ Kl,
                             __bf16* __restrict__ Vth, __bf16* __restrict__ Vtl) {
    int idx = blockIdx.x * blockDim.x + threadIdx.x;
    if (idx >= (LTP - LT) * 512) return;
    int r = idx / 512, c = idx % 512;
    Kh[(size_t)(LT + r) * DM + c] = (__bf16)0.0f;
    Kl[(size_t)(LT + r) * DM + c] = (__bf16)0.0f;
    Vth[(size_t)c * LTP + LT + r] = (__bf16)0.0f;
    Vtl[(size_t)c * LTP + LT + r] = (__bf16)0.0f;
}

// ---------------- LN + AdaLN modulate -> pre-split bf16 hi/lo planes --------
template<bool PL>
__global__ __launch_bounds__(256) void lnmod_kernel(const float* __restrict__ xf,
                                                    const __bf16* __restrict__ xh,
                                                    const __bf16* __restrict__ xl,
                                                    __bf16* __restrict__ yh,
                                                    __bf16* __restrict__ yl,
                                                    const float* __restrict__ params,
                                                    int mod_off) {
    int T = blockIdx.x;
    int tid = threadIdx.x;
    int r = (T < LZ) ? (T / SEQ) : 6;
    const float* prow = params + r * 3072 + mod_off;
    size_t base = (size_t)T * DM;
    float v0, v1;
    if constexpr (PL) {
        v0 = (float)xh[base + tid] + (float)xl[base + tid];
        v1 = (float)xh[base + tid + 256] + (float)xl[base + tid + 256];
    } else {
        v0 = xf[base + tid];
        v1 = xf[base + tid + 256];
    }
    float s_ = v0 + v1, q_ = v0 * v0 + v1 * v1;
#pragma unroll
    for (int off = 32; off; off >>= 1) {
        s_ += __shfl_down(s_, off);
        q_ += __shfl_down(q_, off);
    }
    __shared__ float sh[8];
    int wave = tid >> 6, lane = tid & 63;
    if (lane == 0) { sh[wave] = s_; sh[4 + wave] = q_; }
    __syncthreads();
    float sum = sh[0] + sh[1] + sh[2] + sh[3];
    float sq = sh[4] + sh[5] + sh[6] + sh[7];
    float mu = sum * (1.0f / 512.0f);
    float var = sq * (1.0f / 512.0f) - mu * mu;
    float rstd = rsqrtf(var + 1e-5f);
    float y0 = (v0 - mu) * rstd * (1.0f + prow[tid]) + prow[512 + tid];
    float y1 = (v1 - mu) * rstd * (1.0f + prow[tid + 256]) + prow[512 + tid + 256];
    __bf16 h0 = (__bf16)y0, h1 = (__bf16)y1;
    yh[base + tid] = h0;
    yl[base + tid] = (__bf16)(y0 - (float)h0);
    yh[base + tid + 256] = h1;
    yl[base + tid + 256] = (__bf16)(y1 - (float)h1);
}

// ================= split-precision bf16 MFMA GEMM family =====================
#define MFMA3(accv, ah, al, bh, bl)                                            \
    accv = __builtin_amdgcn_mfma_f32_16x16x32_bf16(al, bh, accv, 0, 0, 0);     \
    accv = __builtin_amdgcn_mfma_f32_16x16x32_bf16(ah, bl, accv, 0, 0, 0);     \
    accv = __builtin_amdgcn_mfma_f32_16x16x32_bf16(ah, bh, accv, 0, 0, 0);

// ---- per-layer weight pre-split/transpose/tile -----------------------------
// Tile = [2(plane)][64(nrow)][32(kcol)] bf16, UNPADDED (8192 B), with the
// bank XOR baked into the column layout: dest slot = (srcslot ^ ((row>>1)&3)).
// Frag reads apply the same XOR -> 2-way bank aliasing (free).
// Wp float-offset regions: q 0 | k 262144 | v 524288 | o 786432 |
//                          glu 1048576 | ff 3145728 | end 4194304 (16.8 MB)
__global__ __launch_bounds__(256) void wprep_kernel(const float* __restrict__ Wq,
                                                    const float* __restrict__ Wk,
                                                    const float* __restrict__ Wv,
                                                    const float* __restrict__ Wo,
                                                    const float* __restrict__ Wglu,
                                                    const float* __restrict__ Wff,
                                                    float* __restrict__ Wp) {
    __shared__ __align__(16) __bf16 T[2][64][32];
    int id = blockIdx.x, t = threadIdx.x;
    const float* src;
    int N, nsub, kt;
    size_t dstf;
    if (id < 512) {
        int mat = id >> 7, rem = id & 127;
        nsub = rem >> 4; kt = rem & 15; N = 512;
        src = mat == 0 ? Wq : mat == 1 ? Wk : mat == 2 ? Wv : Wo;
        dstf = (size_t)mat * 262144 + (size_t)(nsub * 16 + kt) * 2048;
    } else if (id < 1536) {
        int rem = id - 512;
        nsub = rem >> 4; kt = rem & 15; N = 4096; src = Wglu;
        dstf = 1048576 + (size_t)(nsub * 16 + kt) * 2048;
    } else {
        int rem = id - 1536;
        nsub = rem >> 6; kt = rem & 63; N = 512; src = Wff;
        dstf = 3145728 + (size_t)(nsub * 64 + kt) * 2048;
    }
    int r = t >> 2;
    int s = t & 3;
    int ds = (s ^ ((r >> 1) & 3)) * 8;   // baked XOR slot
#pragma unroll
    for (int j = 0; j < 8; ++j) {
        int c = s * 8 + j;
        float x = src[(size_t)(kt * 32 + c) * N + nsub * 64 + r];
        __bf16 h = (__bf16)x;
        T[0][r][ds + j] = h;
        T[1][r][ds + j] = (__bf16)(x - (float)h);
    }
    __syncthreads();
    float4* d = (float4*)(Wp + dstf);
    const float4* s4 = (const float4*)(&T[0][0][0]);
    for (int i2 = t; i2 < 512; i2 += 256) d[i2] = s4[i2];
}

#define M_QKV 0
#define M_GATE1 1
#define M_GLU 2
#define M_GATE2 3

// Uniform GEMM: BM = NI*32, BN = 128 output cols (two 64-col B subtiles;
// GLU: 64 a-cols + 64 paired g-cols), BK=32, 4 waves (2M x 2N).
// Both A and B staged via global_load_lds (A: per-lane XOR-swizzled source;
// B: XOR pre-baked by wprep); frag reads apply the matching XOR.
// Double-buffered; next tile's DMA issued BEFORE current MFMAs so the
// barrier's vmcnt(0) drain overlaps compute. One barrier per k-step.
template<int MODE, int NI>
__global__ __launch_bounds__(256) void gemm_kernel(
    const __bf16* __restrict__ Aph, const __bf16* __restrict__ Apl,
    const char* __restrict__ Wbase, int KT, int Krow,
    const float* __restrict__ b0, const float* __restrict__ b1,
    const float* __restrict__ b2,
    float* __restrict__ C0,
    __bf16* __restrict__ Oh, __bf16* __restrict__ Ol,
    __bf16* __restrict__ O2h, __bf16* __restrict__ O2l,
    __bf16* __restrict__ O3h, __bf16* __restrict__ O3l,
    const __bf16* __restrict__ Xh, const __bf16* __restrict__ Xl,
    const float* __restrict__ params, int M) {
    constexpr int BM = NI * 32;
    __shared__ __align__(16) __bf16 Alds[2][2][BM][32];        // buf, plane
    __shared__ __align__(16) __bf16 Blds[2][2][2][64][32];     // buf, sub, plane
    int tid = threadIdx.x;
    int w = tid >> 6, lane = tid & 63;
    int q = lane >> 4, lr = lane & 15;
    // XCD-chunked bijective swizzle (m-fastest within an XCD -> B L2-local)
    int nwg = gridDim.x * gridDim.y;
    int lin = blockIdx.y * gridDim.x + blockIdx.x;
    int qq = nwg >> 3, rr = nwg & 7;
    int xcd = lin & 7, ix = lin >> 3;
    int wg = (xcd < rr) ? xcd * (qq + 1) + ix : rr * (qq + 1) + (xcd - rr) * qq + ix;
    int mb = wg % gridDim.x;
    int nb = wg / gridDim.x;
    int m0 = mb * BM;
    const char* sb0;
    const char* sb1;
    if constexpr (MODE == M_QKV) {
        int sel = nb >> 2;
        const char* mbp = Wbase + (size_t)sel * 1048576;
        sb0 = mbp + (size_t)(2 * (nb & 3)) * 131072;
        sb1 = mbp + (size_t)(2 * (nb & 3) + 1) * 131072;
    } else if constexpr (MODE == M_GLU) {
        sb0 = Wbase + (size_t)nb * 131072;              // a-cols subtile
        sb1 = Wbase + (size_t)(32 + nb) * 131072;       // g-cols subtile
    } else {
        sb0 = Wbase + (size_t)(2 * nb) * (size_t)KT * 8192;
        sb1 = Wbase + (size_t)(2 * nb + 1) * (size_t)KT * 8192;
    }
    int wm = (w >> 1) * (BM / 2);

    auto stage = [&](int sbuf, int kt) {
        const char* k0 = sb0 + (size_t)kt * 8192;
        const char* k1 = sb1 + (size_t)kt * 8192;
        char* bl = (char*)(&Blds[sbuf][0][0][0][0]);
        for (int idx = w; idx < 16; idx += 4) {
            int sub = idx >> 3, c = idx & 7;
            const char* g = (sub ? k1 : k0) + (c << 10) + (lane << 4);
            __builtin_amdgcn_global_load_lds((const unsigned int*)g,
                (unsigned int*)(bl + sub * 8192 + (c << 10)), 16, 0, 0);
        }
        char* al = (char*)(&Alds[sbuf][0][0][0]);
        for (int idx = w; idx < NI * 4; idx += 4) {
            int p = idx & 1, c = idx >> 1;
            int row = c * 16 + (lane >> 2);
            int ss = (lane & 3) ^ ((row >> 1) & 3);
            int mrow = m0 + row;
            if (mrow > M - 1) mrow = M - 1;
            const __bf16* ap = (p ? Apl : Aph) + (size_t)mrow * Krow + kt * 32 + ss * 8;
            __builtin_amdgcn_global_load_lds((const unsigned int*)ap,
                (unsigned int*)(al + p * (NI * 2048) + (c << 10)), 16, 0, 0);
        }
    };

    f32x4 acc[NI][4];
#pragma unroll
    for (int i = 0; i < NI; ++i)
#pragma unroll
        for (int j = 0; j < 4; ++j)
#pragma unroll
            for (int r = 0; r < 4; ++r) acc[i][j][r] = 0.0f;

    stage(0, 0);
    __syncthreads();
    for (int kt = 0; kt < KT; ++kt) {
        int buf = kt & 1;
        if (kt + 1 < KT) stage(buf ^ 1, kt + 1);   // prefetch: drained by barrier
        bf16x8 afh[NI], afl[NI], bh[4], bl4[4];
        const char* ab = (const char*)(&Alds[buf][0][0][0]);
#pragma unroll
        for (int i = 0; i < NI; ++i) {
            int row = wm + i * 16 + lr;
            int off = (q * 16) ^ (((row >> 1) & 3) << 4);
            afh[i] = *(const bf16x8*)(ab + row * 64 + off);
            afl[i] = *(const bf16x8*)(ab + NI * 2048 + row * 64 + off);
        }
        const char* bb = (const char*)(&Blds[buf][0][0][0][0]);
#pragma unroll
        for (int j = 0; j < 4; ++j) {
            int bsub, brow;
            if constexpr (MODE == M_GLU) {
                bsub = j >> 1;
                brow = (w & 1) * 32 + (j & 1) * 16 + lr;
            } else {
                bsub = w & 1;
                brow = j * 16 + lr;
            }
            int off = (q * 16) ^ (((brow >> 1) & 3) << 4);
            bh[j] = *(const bf16x8*)(bb + bsub * 8192 + brow * 64 + off);
            bl4[j] = *(const bf16x8*)(bb + bsub * 8192 + 4096 + brow * 64 + off);
        }
#pragma unroll
        for (int i = 0; i < NI; ++i)
#pragma unroll
            for (int j = 0; j < 4; ++j) {
                MFMA3(acc[i][j], afh[i], afl[i], bh[j], bl4[j]);
            }
        __syncthreads();
    }

    if constexpr (MODE == M_QKV) {
        int sel = nb >> 2;
        int c0 = (nb & 3) * 128 + (w & 1) * 64;
        if (sel == 2) {
            // V^T hi/lo planes: Vt[(n)][token], 8B vector stores over r
#pragma unroll
            for (int i = 0; i < NI; ++i) {
                int mb2 = m0 + wm + i * 16 + q * 4;
#pragma unroll
                for (int j = 0; j < 4; ++j) {
                    int n = c0 + j * 16 + lr;
                    bf16x4 h4, l4;
#pragma unroll
                    for (int r = 0; r < 4; ++r) {
                        float v = acc[i][j][r] + b2[n];
                        __bf16 hh = (__bf16)v;
                        h4[r] = hh;
                        l4[r] = (__bf16)(v - (float)hh);
                    }
                    if (mb2 + 3 < M) {
                        *(bf16x4*)(O3h + (size_t)n * LTP + mb2) = h4;
                        *(bf16x4*)(O3l + (size_t)n * LTP + mb2) = l4;
                    } else {
#pragma unroll
                        for (int r = 0; r < 4; ++r)
                            if (mb2 + r < M) {
                                O3h[(size_t)n * LTP + mb2 + r] = h4[r];
                                O3l[(size_t)n * LTP + mb2 + r] = l4[r];
                            }
                    }
                }
            }
        } else {
            const float* bias = sel == 0 ? b0 : b1;
            __bf16* Dh = sel == 0 ? Oh : O2h;
            __bf16* Dl = sel == 0 ? Ol : O2l;
            float scale = sel == 0 ? 0.125f : 1.0f;   // fold softmax scale into Q
#pragma unroll
            for (int i = 0; i < NI; ++i)
#pragma unroll
                for (int r = 0; r < 4; ++r) {
                    int m = m0 + wm + i * 16 + q * 4 + r;
                    if (m >= M) continue;
#pragma unroll
                    for (int j = 0; j < 4; ++j) {
                        int n = c0 + j * 16 + lr;
                        float v = (acc[i][j][r] + bias[n]) * scale;
                        __bf16 hh = (__bf16)v;
                        Dh[(size_t)m * DM + n] = hh;
                        Dl[(size_t)m * DM + n] = (__bf16)(v - (float)hh);
                    }
                }
        }
        return;
    }

#pragma unroll
    for (int i = 0; i < NI; ++i)
#pragma unroll
        for (int r = 0; r < 4; ++r) {
            int m = m0 + wm + i * 16 + q * 4 + r;
            if (m >= M) continue;
            if constexpr (MODE == M_GATE1) {
                int r6 = (m < LZ) ? (m / SEQ) : 6;
                const float* g1 = params + r6 * 3072 + 2048;
                int c0 = nb * 128 + (w & 1) * 64;
#pragma unroll
                for (int j = 0; j < 4; ++j) {
                    int n = c0 + j * 16 + lr;
                    size_t o = (size_t)m * 512 + n;
                    float x = (float)Xh[o] + (float)Xl[o];
                    float v = x * g1[n] + acc[i][j][r] + b0[n];
                    __bf16 hh = (__bf16)v;
                    Oh[o] = hh;
                    Ol[o] = (__bf16)(v - (float)hh);
                }
            } else if constexpr (MODE == M_GLU) {
#pragma unroll
                for (int j = 0; j < 2; ++j) {
                    int n = nb * 64 + (w & 1) * 32 + j * 16 + lr;
                    float a = acc[i][j][r] + b0[n];
                    float g = acc[i][j + 2][r] + b0[2048 + n];
                    float gel = 0.5f * g * (1.0f + erff(g * 0.70710678118654752f));
                    float v = a * gel;
                    size_t o = (size_t)m * 2048 + n;
                    __bf16 hh = (__bf16)v;
                    Oh[o] = hh;
                    Ol[o] = (__bf16)(v - (float)hh);
                }
            } else {
                int r6 = (m < LZ) ? (m / SEQ) : 6;
                const float* g2 = params + r6 * 3072 + 2560;
                int c0 = nb * 128 + (w & 1) * 64;
#pragma unroll
                for (int j = 0; j < 4; ++j) {
                    int n = c0 + j * 16 + lr;
                    C0[(size_t)m * 512 + n] = (acc[i][j][r] + b0[n]) * g2[n];
                }
            }
        }
}

// ---- flash attention: all operands pre-split bf16 planes -------------------
__global__ __launch_bounds__(256) void fattn_kernel(
    const __bf16* __restrict__ Qph, const __bf16* __restrict__ Qpl,
    const __bf16* __restrict__ Kph, const __bf16* __restrict__ Kpl,
    const __bf16* __restrict__ Vph, const __bf16* __restrict__ Vpl,
    __bf16* __restrict__ Oh, __bf16* __restrict__ Ol) {
    __shared__ __align__(16) __bf16 Ksh[2][64][64];
    __shared__ __align__(16) __bf16 Vsh[2][64][64];
    __shared__ __align__(16) __bf16 Ph[4][16][72], Pl[4][16][72];
    int tid = threadIdx.x;
    int w = tid >> 6, lane = tid & 63;
    int lq = lane & 15, lg = lane >> 4;
    int hoff = blockIdx.z * DH;
    int qbase, base0, len0, base1, len1;
    if (blockIdx.y < 6) {
        int f = blockIdx.y;
        qbase = f * SEQ;
        base0 = f * SEQ; len0 = SEQ;
        int jl = f - 4; if (jl < 0) jl = 0;
        base1 = LZ + jl * SEQ; len1 = (f - jl) * SEQ;
    } else {
        int f = blockIdx.y - 6;
        qbase = LZ + f * SEQ;
        base0 = LZ; len0 = (f + 1) * SEQ;
        base1 = 0; len1 = 0;
    }
    int q0 = blockIdx.x * 64;
    int qvalid = SEQ - q0; if (qvalid > 64) qvalid = 64;

    bf16x8 qfh[2], qfl[2];
    {
        int qr = w * 16 + lq;
        int tok = qbase + q0 + ((qr < qvalid) ? qr : 0);
        const __bf16* qph = Qph + (size_t)tok * DM + hoff + lg * 8;
        const __bf16* qpl = Qpl + (size_t)tok * DM + hoff + lg * 8;
#pragma unroll
        for (int s = 0; s < 2; ++s) {
            qfh[s] = *(const bf16x8*)(qph + s * 32);
            qfl[s] = *(const bf16x8*)(qpl + s * 32);
        }
    }
    f32x4 acc[4];
#pragma unroll
    for (int n = 0; n < 4; ++n)
#pragma unroll
        for (int r = 0; r < 4; ++r) acc[n][r] = 0.0f;
    float m_i = -1e30f, l_i = 0.0f;
    int slot = lane & 7, rsub = lane >> 3;

    for (int rng = 0; rng < 2; ++rng) {
        int base = rng ? base1 : base0;
        int len = rng ? len1 : len0;
        if (len == 0) continue;
        int tend = base + len;
        for (int t = base & ~63; t < tend; t += 64) {
            int lo = base - t; if (lo < 0) lo = 0;
            int hi = tend - t; if (hi > 64) hi = 64;
            __syncthreads();
#pragma unroll
            for (int ii = 0; ii < 4; ++ii) {
                int idx = w + ii * 4;
                int p = idx >> 3, c = idx & 7;
                int row = c * 8 + rsub;
                const __bf16* g = (p ? Kpl : Kph) +
                    (size_t)(t + row) * DM + hoff + (slot ^ (row & 7)) * 8;
                __builtin_amdgcn_global_load_lds((const unsigned int*)g,
                    (unsigned int*)((char*)(&Ksh[p][0][0]) + c * 1024), 16, 0, 0);
            }
#pragma unroll
            for (int ii = 0; ii < 4; ++ii) {
                int idx = w + ii * 4;
                int p = idx >> 3, c = idx & 7;
                int d = c * 8 + rsub;
                const __bf16* g = (p ? Vpl : Vph) +
                    (size_t)(hoff + d) * LTP + t + (slot ^ (d & 7)) * 8;
                __builtin_amdgcn_global_load_lds((const unsigned int*)g,
                    (unsigned int*)((char*)(&Vsh[p][0][0]) + c * 1024), 16, 0, 0);
            }
            __syncthreads();
            f32x4 st[4];
#pragma unroll
            for (int sub = 0; sub < 4; ++sub)
#pragma unroll
                for (int r = 0; r < 4; ++r) st[sub][r] = 0.0f;
#pragma unroll
            for (int sub = 0; sub < 4; ++sub) {
                int row = sub * 16 + lq;
#pragma unroll
                for (int s = 0; s < 2; ++s) {
                    int sl = ((s * 4 + lg) ^ (row & 7)) * 8;
                    bf16x8 kfh = *(const bf16x8*)(&Ksh[0][row][sl]);
                    bf16x8 kfl = *(const bf16x8*)(&Ksh[1][row][sl]);
                    MFMA3(st[sub], kfh, kfl, qfh[s], qfl[s]);
                }
            }
            float p[16];
            float rmax = -1e30f;
#pragma unroll
            for (int sub = 0; sub < 4; ++sub)
#pragma unroll
                for (int r = 0; r < 4; ++r) {
                    int kk = sub * 16 + lg * 4 + r;
                    float sv = (kk >= lo && kk < hi) ? st[sub][r] : -1e30f;
                    p[sub * 4 + r] = sv;
                    rmax = fmaxf(rmax, sv);
                }
            rmax = fmaxf(rmax, __shfl_xor(rmax, 16));
            rmax = fmaxf(rmax, __shfl_xor(rmax, 32));
            float mnew = fmaxf(m_i, rmax);
            float alpha = __expf(m_i - mnew);
            float rsum = 0.0f;
#pragma unroll
            for (int i2 = 0; i2 < 16; ++i2) {
                p[i2] = __expf(p[i2] - mnew);
                rsum += p[i2];
            }
            rsum += __shfl_xor(rsum, 16);
            rsum += __shfl_xor(rsum, 32);
            l_i = l_i * alpha + rsum;
            m_i = mnew;
            float ar[4];
#pragma unroll
            for (int r = 0; r < 4; ++r) ar[r] = __shfl(alpha, lg * 4 + r);
#pragma unroll
            for (int n = 0; n < 4; ++n)
#pragma unroll
                for (int r = 0; r < 4; ++r) acc[n][r] *= ar[r];
#pragma unroll
            for (int sub = 0; sub < 4; ++sub) {
                bf16x4 h4, l4;
#pragma unroll
                for (int r = 0; r < 4; ++r) {
                    float x = p[sub * 4 + r];
                    __bf16 hh = (__bf16)x;
                    h4[r] = hh;
                    l4[r] = (__bf16)(x - (float)hh);
                }
                *(bf16x4*)&Ph[w][lq][sub * 16 + lg * 4] = h4;
                *(bf16x4*)&Pl[w][lq][sub * 16 + lg * 4] = l4;
            }
            bf16x8 pah[2], pal[2];
#pragma unroll
            for (int s = 0; s < 2; ++s) {
                pah[s] = *(const bf16x8*)(&Ph[w][lq][s * 32 + lg * 8]);
                pal[s] = *(const bf16x8*)(&Pl[w][lq][s * 32 + lg * 8]);
            }
#pragma unroll
            for (int n = 0; n < 4; ++n) {
                int row = n * 16 + lq;
#pragma unroll
                for (int s = 0; s < 2; ++s) {
                    int sl = ((s * 4 + lg) ^ (row & 7)) * 8;
                    bf16x8 vfh = *(const bf16x8*)(&Vsh[0][row][sl]);
                    bf16x8 vfl = *(const bf16x8*)(&Vsh[1][row][sl]);
                    MFMA3(acc[n], pah[s], pal[s], vfh, vfl);
                }
            }
        }
    }
    float linv[4];
#pragma unroll
    for (int r = 0; r < 4; ++r) linv[r] = 1.0f / __shfl(l_i, lg * 4 + r);
#pragma unroll
    for (int r = 0; r < 4; ++r) {
        int qr = w * 16 + lg * 4 + r;
        if (qr < qvalid) {
            size_t ob = (size_t)(qbase + q0 + qr) * DM + hoff;
#pragma unroll
            for (int n = 0; n < 4; ++n) {
                float v = acc[n][r] * linv[r];
                __bf16 hh = (__bf16)v;
                Oh[ob + n * 16 + lq] = hh;
                Ol[ob + n * 16 + lq] = (__bf16)(v - (float)hh);
            }
        }
    }
}

// ---------------- unpatch to FP32 output ------------------
__global__ void unpatch_kernel(const float* __restrict__ state,
                               const float* __restrict__ Wu,
                               const float* __restrict__ bu,
                               float* __restrict__ out) {
    int idx = blockIdx.x * blockDim.x + threadIdx.x;
    if (idx >= DURZ * 3 * 32 * 32) return;
    int w = idx & 31, hh = (idx >> 5) & 31, c = (idx >> 10) % 3, f = idx / (3 * 1024);
    int t = (hh >> 1) * 16 + (w >> 1);
    int j = c * 4 + (hh & 1) * 2 + (w & 1);
    const float* xr = state + (size_t)(f * SEQ + t) * DM;
    float acc = bu[j];
    for (int k = 0; k < DM; ++k) acc += xr[k] * Wu[k * 12 + j];
    out[idx] = acc;
}

extern "C" void kernel_launch(void* const* d_in, const int* in_sizes, int n_in,
                              void* d_out, int out_size, void* d_ws, size_t ws_size,
                              hipStream_t stream) {
    static const int expected_sizes[32] = {
        18432, 15360, 6, 6,
        6144, 512, 6144, 12,
        512, 131072, 1536, 512000,
        3145728, 6144, 3145728, 6144,
        1572864, 3072, 1572864, 3072,
        1572864, 3072, 1572864, 3072,
        1572864, 3072, 1572864, 3072,
        12582912, 24576, 6291456, 3072
    };
    if (n_in != 32) {
        fill_kernel<<<(18432 + 255) / 256, 256, 0, stream>>>((float*)d_out, 18432, 3.0f);
        return;
    }
    for (int i = 0; i < 32; ++i) {
        if (in_sizes[i] != expected_sizes[i]) {
            fill_kernel<<<(18432 + 255) / 256, 256, 0, stream>>>((float*)d_out, 18432,
                                                                 4.0f + (float)i);
            return;
        }
    }

    const float* z = (const float*)d_in[0];
    const float* frames = (const float*)d_in[1];
    const int* actions = (const int*)d_in[2];
    const int* ts = (const int*)d_in[3];
    const float* W_patch = (const float*)d_in[4];
    const float* b_patch = (const float*)d_in[5];
    const float* W_unpatch = (const float*)d_in[6];
    const float* b_unpatch = (const float*)d_in[7];
    const float* registers = (const float*)d_in[8];
    const float* pe_grid = (const float*)d_in[9];
    const float* action_emb = (const float*)d_in[10];
    const float* time_emb = (const float*)d_in[11];
    const float* W_mod1 = (const float*)d_in[12];
    const float* b_mod1 = (const float*)d_in[13];
    const float* W_mod2 = (const float*)d_in[14];
    const float* b_mod2 = (const float*)d_in[15];
    const float* W_q = (const float*)d_in[16];
    const float* b_q = (const float*)d_in[17];
    const float* W_k = (const float*)d_in[18];
    const float* b_k = (const float*)d_in[19];
    const float* W_v = (const float*)d_in[20];
    const float* b_v = (const float*)d_in[21];
    const float* W_o = (const float*)d_in[22];
    const float* b_o = (const float*)d_in[23];
    const float* W_g1 = (const float*)d_in[24];
    const float* b_g1 = (const float*)d_in[25];
    const float* W_g2 = (const float*)d_in[26];
    const float* b_g2 = (const float*)d_in[27];
    const float* W_geglu = (const float*)d_in[28];
    const float* b_geglu = (const float*)d_in[29];
    const float* W_ffout = (const float*)d_in[30];
    const float* b_ffout = (const float*)d_in[31];

    const size_t S = (size_t)LT * DM;          // 1,447,424 floats
    const size_t PLE = (size_t)LTP * DM;       // plane bf16 elems = 1,474,560
    const size_t PLF = PLE / 2;                // plane floats = 737,280
    size_t need = (4 * S + 6 * PLF + 129024 + 7168 + 4194304) * sizeof(float);
    if (ws_size < need) {
        fill_kernel<<<(18432 + 255) / 256, 256, 0, stream>>>((float*)d_out, 18432, 40.0f);
        return;
    }
    float* ws = (float*)d_ws;
    float* state = ws;                              // [0, 1S)
    __bf16* xnh = (__bf16*)(ws + S);                // [1S, 1.5S)
    __bf16* xnl = (__bf16*)(ws + S + S / 2);        // [1.5S, 2S)
    __bf16* Qh = (__bf16*)(ws + 2 * S);             // 6 planes of PLE bf16
    __bf16* Ql = Qh + PLE;
    __bf16* Kh = Qh + 2 * PLE;
    __bf16* Kl = Qh + 3 * PLE;
    __bf16* Vth = Qh + 4 * PLE;
    __bf16* Vtl = Qh + 5 * PLE;
    float* aoff = ws + 2 * S + 6 * PLF;
    __bf16* atth = (__bf16*)aoff;                   // S bf16
    __bf16* attl = atth + S;
    __bf16* y2h = (__bf16*)(aoff + S);
    __bf16* y2l = y2h + S;
    __bf16* Hph = (__bf16*)(ws + 2 * S);            // overlay (planes+att dead)
    __bf16* Hpl = Hph + (size_t)LT * HIDDEN;
    float* params = aoff + 2 * S;
    float* condraw = params + 129024;
    float* condsilu = condraw + 3584;
    float* wp = condsilu + 3584;                    // 4,194,304 floats

    embed_kernel<<<LT, 256, 0, stream>>>(z, frames, actions, W_patch, b_patch,
                                         registers, pe_grid, action_emb, state);
    cond_kernel<<<(7 * 512 + 255) / 256, 256, 0, stream>>>(ts, time_emb, condraw, condsilu);
    params_kernel<<<(6 * 7 * 3072 + 255) / 256, 256, 0, stream>>>(
        condraw, condsilu, W_mod1, b_mod1, W_mod2, b_mod2, W_g1, b_g1, W_g2, b_g2, params);
    ztail_kernel<<<((LTP - LT) * 512 + 255) / 256, 256, 0, stream>>>(Kh, Kl, Vth, Vtl);

    dim3 gqkv(45, 12);
    dim3 ggate1(45, 4);
    dim3 gglu(23, 32);
    dim3 ggate2(45, 4);
    dim3 gattn(5, 11, NHEADS);
    for (int i = 0; i < 6; ++i) {
        const float* P = params + i * 21504;
        wprep_kernel<<<2048, 256, 0, stream>>>(
            W_q + (size_t)i * DM * DM, W_k + (size_t)i * DM * DM,
            W_v + (size_t)i * DM * DM, W_o + (size_t)i * DM * DM,
            W_geglu + (size_t)i * DM * 4096, W_ffout + (size_t)i * HIDDEN * DM, wp);
        lnmod_kernel<false><<<LT, 256, 0, stream>>>(state, nullptr, nullptr,
                                                    xnh, xnl, P, 0);
        gemm_kernel<M_QKV, 2><<<gqkv, 256, 0, stream>>>(
            xnh, xnl, (const char*)wp, 16, 512,
            b_q + i * DM, b_k + i * DM, b_v + i * DM, nullptr,
            Qh, Ql, Kh, Kl, Vth, Vtl, nullptr, nullptr, nullptr, LT);
        fattn_kernel<<<gattn, 256, 0, stream>>>(Qh, Ql, Kh, Kl, Vth, Vtl, atth, attl);
        gemm_kernel<M_GATE1, 2><<<ggate1, 256, 0, stream>>>(
            atth, attl, (const char*)(wp + 786432), 16, 512,
            b_o + i * DM, nullptr, nullptr, nullptr,
            y2h, y2l, nullptr, nullptr, nullptr, nullptr, xnh, xnl, P, LT);
        lnmod_kernel<true><<<LT, 256, 0, stream>>>(nullptr, y2h, y2l,
                                                   xnh, xnl, P, 1024);
        gemm_kernel<M_GLU, 4><<<gglu, 256, 0, stream>>>(
            xnh, xnl, (const char*)(wp + 1048576), 16, 512,
            b_geglu + (size_t)i * 4096, nullptr, nullptr, nullptr,
            Hph, Hpl, nullptr, nullptr, nullptr, nullptr, nullptr, nullptr, nullptr, LT);
        gemm_kernel<M_GATE2, 2><<<ggate2, 256, 0, stream>>>(
            Hph, Hpl, (const char*)(wp + 3145728), 64, 2048,
            b_ffout + i * DM, nullptr, nullptr, state,
            nullptr, nullptr, nullptr, nullptr, nullptr, nullptr,
            nullptr, nullptr, P, LT);
    }
    unpatch_kernel<<<(DURZ * 3 * 32 * 32 + 255) / 256, 256, 0, stream>>>(
        state, W_unpatch, b_unpatch, (float*)d_out);
}

// Round 7
// 1744.853 us; speedup vs baseline: 1.1392x; 1.0149x over previous
//
#include <hip/hip_runtime.h>
#include <hip/hip_bf16.h>
#include <math.h>

// ---- problem constants ----
#define DURZ 6
#define DURX 5
#define SEQ 257
#define LZ 1542   // 6*257 zr tokens
#define LX 1285   // 5*257 xa tokens
#define LT 2827   // LZ+LX
#define LTP 2880  // LT rounded up to 64 (plane row pad for aligned KV tiles)
#define DM 512
#define NHEADS 8
#define DH 64
#define HIDDEN 2048

typedef __bf16 bf16x8 __attribute__((ext_vector_type(8)));
typedef __bf16 bf16x4 __attribute__((ext_vector_type(4)));
typedef float f32x4 __attribute__((ext_vector_type(4)));

// ---------------- sentinel fill (diagnostic readout channel) ----------------
__global__ void fill_kernel(float* __restrict__ out, int n, float v) {
    int i = blockIdx.x * blockDim.x + threadIdx.x;
    if (i < n) out[i] = v;
}

// ---------------- embed ----------------
__global__ void embed_kernel(const float* __restrict__ z,
                             const float* __restrict__ frames,
                             const int* __restrict__ actions,
                             const float* __restrict__ W_patch,
                             const float* __restrict__ b_patch,
                             const float* __restrict__ registers,
                             const float* __restrict__ pe,
                             const float* __restrict__ action_emb,
                             float* __restrict__ state) {
    int T = blockIdx.x;
    int tid = threadIdx.x;
    bool is_z = T < LZ;
    int T2 = is_z ? T : T - LZ;
    int f = T2 / SEQ, t = T2 % SEQ;
    if (t < 256) {
        const float* src = is_z ? z : frames;
        int hp = t >> 4, wp = t & 15;
        float pv[12];
#pragma unroll
        for (int c = 0; c < 3; c++)
#pragma unroll
            for (int ph = 0; ph < 2; ph++)
#pragma unroll
                for (int pw = 0; pw < 2; pw++)
                    pv[c * 4 + ph * 2 + pw] =
                        src[((f * 3 + c) * 32 + (hp * 2 + ph)) * 32 + (wp * 2 + pw)];
        for (int d = tid; d < DM; d += 256) {
            float acc = b_patch[d];
#pragma unroll
            for (int j = 0; j < 12; j++) acc += pv[j] * W_patch[j * DM + d];
            acc += pe[t * DM + d];
            state[T * DM + d] = acc;
        }
    } else if (is_z) {
        for (int d = tid; d < DM; d += 256) state[T * DM + d] = registers[d];
    } else {
        int a = actions[f];
        for (int d = tid; d < DM; d += 256) state[T * DM + d] = action_emb[a * DM + d];
    }
}

// ---------------- cond vectors ----------------
__global__ void cond_kernel(const int* __restrict__ ts,
                            const float* __restrict__ time_emb,
                            float* __restrict__ condraw,
                            float* __restrict__ condsilu) {
    int idx = blockIdx.x * blockDim.x + threadIdx.x;
    if (idx >= 7 * 512) return;
    int r = idx >> 9;
    int j = idx & 511;
    int tsr = (r < 6) ? ts[r] : 0;
    float x = time_emb[tsr * 512 + j];
    condraw[idx] = x;
    condsilu[idx] = x / (1.0f + expf(-x));
}

// ---------------- params[i][r][c] ----------------
// Serial-latency fix: compile-time LDW + 4 accumulators + unroll-8 keeps
// ~32 loads in flight per wave (was 1: rolled loop with runtime ldw at
// ~336 cy/iter). Blocks are segment-uniform (3072/256=12 blocks per (i,r);
// segment boundaries 1024/2048/2560 are multiples of 256).
template<int LDW>
__device__ __forceinline__ float dot512(const float* __restrict__ sh,
                                        const float* __restrict__ W) {
    float a0 = 0.0f, a1 = 0.0f, a2 = 0.0f, a3 = 0.0f;
#pragma unroll 8
    for (int j = 0; j < 512; j += 4) {
        a0 = fmaf(sh[j + 0], W[(size_t)(j + 0) * LDW], a0);
        a1 = fmaf(sh[j + 1], W[(size_t)(j + 1) * LDW], a1);
        a2 = fmaf(sh[j + 2], W[(size_t)(j + 2) * LDW], a2);
        a3 = fmaf(sh[j + 3], W[(size_t)(j + 3) * LDW], a3);
    }
    return (a0 + a1) + (a2 + a3);
}

__global__ __launch_bounds__(256) void params_kernel(
    const float* __restrict__ condraw, const float* __restrict__ condsilu,
    const float* __restrict__ W_mod1, const float* __restrict__ b_mod1,
    const float* __restrict__ W_mod2, const float* __restrict__ b_mod2,
    const float* __restrict__ W_g1, const float* __restrict__ b_g1,
    const float* __restrict__ W_g2, const float* __restrict__ b_g2,
    float* __restrict__ params) {
    __shared__ float sh[512];
    int tid = threadIdx.x;
    int idx0 = blockIdx.x * 256;           // 504 blocks cover 6*7*3072 exactly
    int i = idx0 / 21504;
    int rem = idx0 % 21504;
    int r = rem / 3072;
    int c0 = rem % 3072;                   // segment-uniform per block
    int c = c0 + tid;
    const float* cv = (c0 < 2048 ? condsilu : condraw) + r * 512;
    sh[tid] = cv[tid];
    sh[tid + 256] = cv[tid + 256];
    __syncthreads();
    float acc;
    if (c0 < 1024) {
        acc = b_mod1[i * 1024 + c] +
              dot512<1024>(sh, W_mod1 + (size_t)i * 512 * 1024 + c);
    } else if (c0 < 2048) {
        int cc = c - 1024;
        acc = b_mod2[i * 1024 + cc] +
              dot512<1024>(sh, W_mod2 + (size_t)i * 512 * 1024 + cc);
    } else if (c0 < 2560) {
        int cc = c - 2048;
        acc = b_g1[i * 512 + cc] +
              dot512<512>(sh, W_g1 + (size_t)i * 512 * 512 + cc);
    } else {
        int cc = c - 2560;
        acc = b_g2[i * 512 + cc] +
              dot512<512>(sh, W_g2 + (size_t)i * 512 * 512 + cc);
    }
    params[idx0 + tid] = acc;
}

// ---------------- zero plane tails (once; epilogues never touch rows>=LT) ---
__global__ void ztail_kernel(__bf16* __restrict__ Kh, __bf16* __restrict__ Kl,
                             __bf16* __restrict__ Vth, __bf16* __restrict__ Vtl) {
    int idx = blockIdx.x * blockDim.x + threadIdx.x;
    if (idx >= (LTP - LT) * 512) return;
    int r = idx / 512, c = idx % 512;
    Kh[(size_t)(LT + r) * DM + c] = (__bf16)0.0f;
    Kl[(size_t)(LT + r) * DM + c] = (__bf16)0.0f;
    Vth[(size_t)c * LTP + LT + r] = (__bf16)0.0f;
    Vtl[(size_t)c * LTP + LT + r] = (__bf16)0.0f;
}

// ---------------- LN + AdaLN modulate -> pre-split bf16 hi/lo planes --------
template<bool PL>
__global__ __launch_bounds__(256) void lnmod_kernel(const float* __restrict__ xf,
                                                    const __bf16* __restrict__ xh,
                                                    const __bf16* __restrict__ xl,
                                                    __bf16* __restrict__ yh,
                                                    __bf16* __restrict__ yl,
                                                    const float* __restrict__ params,
                                                    int mod_off) {
    int T = blockIdx.x;
    int tid = threadIdx.x;
    int r = (T < LZ) ? (T / SEQ) : 6;
    const float* prow = params + r * 3072 + mod_off;
    size_t base = (size_t)T * DM;
    float v0, v1;
    if constexpr (PL) {
        v0 = (float)xh[base + tid] + (float)xl[base + tid];
        v1 = (float)xh[base + tid + 256] + (float)xl[base + tid + 256];
    } else {
        v0 = xf[base + tid];
        v1 = xf[base + tid + 256];
    }
    float s_ = v0 + v1, q_ = v0 * v0 + v1 * v1;
#pragma unroll
    for (int off = 32; off; off >>= 1) {
        s_ += __shfl_down(s_, off);
        q_ += __shfl_down(q_, off);
    }
    __shared__ float sh[8];
    int wave = tid >> 6, lane = tid & 63;
    if (lane == 0) { sh[wave] = s_; sh[4 + wave] = q_; }
    __syncthreads();
    float sum = sh[0] + sh[1] + sh[2] + sh[3];
    float sq = sh[4] + sh[5] + sh[6] + sh[7];
    float mu = sum * (1.0f / 512.0f);
    float var = sq * (1.0f / 512.0f) - mu * mu;
    float rstd = rsqrtf(var + 1e-5f);
    float y0 = (v0 - mu) * rstd * (1.0f + prow[tid]) + prow[512 + tid];
    float y1 = (v1 - mu) * rstd * (1.0f + prow[tid + 256]) + prow[512 + tid + 256];
    __bf16 h0 = (__bf16)y0, h1 = (__bf16)y1;
    yh[base + tid] = h0;
    yl[base + tid] = (__bf16)(y0 - (float)h0);
    yh[base + tid + 256] = h1;
    yl[base + tid + 256] = (__bf16)(y1 - (float)h1);
}

// ================= split-precision bf16 MFMA GEMM family =====================
#define MFMA3(accv, ah, al, bh, bl)                                            \
    accv = __builtin_amdgcn_mfma_f32_16x16x32_bf16(al, bh, accv, 0, 0, 0);     \
    accv = __builtin_amdgcn_mfma_f32_16x16x32_bf16(ah, bl, accv, 0, 0, 0);     \
    accv = __builtin_amdgcn_mfma_f32_16x16x32_bf16(ah, bh, accv, 0, 0, 0);

// ---- per-layer weight pre-split/transpose/tile -----------------------------
// Tile = [2(plane)][64(nrow)][32(kcol)] bf16, UNPADDED (8192 B), with the
// bank XOR baked into the column layout: dest slot = (srcslot ^ ((row>>1)&3)).
// Frag reads apply the same XOR -> 2-way bank aliasing (free).
// Wp float-offset regions: q 0 | k 262144 | v 524288 | o 786432 |
//                          glu 1048576 | ff 3145728 | end 4194304 (16.8 MB)
__global__ __launch_bounds__(256) void wprep_kernel(const float* __restrict__ Wq,
                                                    const float* __restrict__ Wk,
                                                    const float* __restrict__ Wv,
                                                    const float* __restrict__ Wo,
                                                    const float* __restrict__ Wglu,
                                                    const float* __restrict__ Wff,
                                                    float* __restrict__ Wp) {
    __shared__ __align__(16) __bf16 T[2][64][32];
    int id = blockIdx.x, t = threadIdx.x;
    const float* src;
    int N, nsub, kt;
    size_t dstf;
    if (id < 512) {
        int mat = id >> 7, rem = id & 127;
        nsub = rem >> 4; kt = rem & 15; N = 512;
        src = mat == 0 ? Wq : mat == 1 ? Wk : mat == 2 ? Wv : Wo;
        dstf = (size_t)mat * 262144 + (size_t)(nsub * 16 + kt) * 2048;
    } else if (id < 1536) {
        int rem = id - 512;
        nsub = rem >> 4; kt = rem & 15; N = 4096; src = Wglu;
        dstf = 1048576 + (size_t)(nsub * 16 + kt) * 2048;
    } else {
        int rem = id - 1536;
        nsub = rem >> 6; kt = rem & 63; N = 512; src = Wff;
        dstf = 3145728 + (size_t)(nsub * 64 + kt) * 2048;
    }
    int r = t >> 2;
    int s = t & 3;
    int ds = (s ^ ((r >> 1) & 3)) * 8;   // baked XOR slot
#pragma unroll
    for (int j = 0; j < 8; ++j) {
        int c = s * 8 + j;
        float x = src[(size_t)(kt * 32 + c) * N + nsub * 64 + r];
        __bf16 h = (__bf16)x;
        T[0][r][ds + j] = h;
        T[1][r][ds + j] = (__bf16)(x - (float)h);
    }
    __syncthreads();
    float4* d = (float4*)(Wp + dstf);
    const float4* s4 = (const float4*)(&T[0][0][0]);
    for (int i2 = t; i2 < 512; i2 += 256) d[i2] = s4[i2];
}

#define M_QKV 0
#define M_GATE1 1
#define M_GLU 2
#define M_GATE2 3

// Uniform GEMM: BM = NI*32, BN = 128 output cols (two 64-col B subtiles;
// GLU: 64 a-cols + 64 paired g-cols), BK=32, 4 waves (2M x 2N).
// Both A and B staged via global_load_lds (A: per-lane XOR-swizzled source;
// B: XOR pre-baked by wprep); frag reads apply the matching XOR.
// Double-buffered; next tile's DMA issued BEFORE current MFMAs so the
// barrier's vmcnt(0) drain overlaps compute. One barrier per k-step.
template<int MODE, int NI>
__global__ __launch_bounds__(256) void gemm_kernel(
    const __bf16* __restrict__ Aph, const __bf16* __restrict__ Apl,
    const char* __restrict__ Wbase, int KT, int Krow,
    const float* __restrict__ b0, const float* __restrict__ b1,
    const float* __restrict__ b2,
    float* __restrict__ C0,
    __bf16* __restrict__ Oh, __bf16* __restrict__ Ol,
    __bf16* __restrict__ O2h, __bf16* __restrict__ O2l,
    __bf16* __restrict__ O3h, __bf16* __restrict__ O3l,
    const __bf16* __restrict__ Xh, const __bf16* __restrict__ Xl,
    const float* __restrict__ params, int M) {
    constexpr int BM = NI * 32;
    __shared__ __align__(16) __bf16 Alds[2][2][BM][32];        // buf, plane
    __shared__ __align__(16) __bf16 Blds[2][2][2][64][32];     // buf, sub, plane
    int tid = threadIdx.x;
    int w = tid >> 6, lane = tid & 63;
    int q = lane >> 4, lr = lane & 15;
    // XCD-chunked bijective swizzle (m-fastest within an XCD -> B L2-local)
    int nwg = gridDim.x * gridDim.y;
    int lin = blockIdx.y * gridDim.x + blockIdx.x;
    int qq = nwg >> 3, rr = nwg & 7;
    int xcd = lin & 7, ix = lin >> 3;
    int wg = (xcd < rr) ? xcd * (qq + 1) + ix : rr * (qq + 1) + (xcd - rr) * qq + ix;
    int mb = wg % gridDim.x;
    int nb = wg / gridDim.x;
    int m0 = mb * BM;
    const char* sb0;
    const char* sb1;
    if constexpr (MODE == M_QKV) {
        int sel = nb >> 2;
        const char* mbp = Wbase + (size_t)sel * 1048576;
        sb0 = mbp + (size_t)(2 * (nb & 3)) * 131072;
        sb1 = mbp + (size_t)(2 * (nb & 3) + 1) * 131072;
    } else if constexpr (MODE == M_GLU) {
        sb0 = Wbase + (size_t)nb * 131072;              // a-cols subtile
        sb1 = Wbase + (size_t)(32 + nb) * 131072;       // g-cols subtile
    } else {
        sb0 = Wbase + (size_t)(2 * nb) * (size_t)KT * 8192;
        sb1 = Wbase + (size_t)(2 * nb + 1) * (size_t)KT * 8192;
    }
    int wm = (w >> 1) * (BM / 2);

    auto stage = [&](int sbuf, int kt) {
        const char* k0 = sb0 + (size_t)kt * 8192;
        const char* k1 = sb1 + (size_t)kt * 8192;
        char* bl = (char*)(&Blds[sbuf][0][0][0][0]);
        for (int idx = w; idx < 16; idx += 4) {
            int sub = idx >> 3, c = idx & 7;
            const char* g = (sub ? k1 : k0) + (c << 10) + (lane << 4);
            __builtin_amdgcn_global_load_lds((const unsigned int*)g,
                (unsigned int*)(bl + sub * 8192 + (c << 10)), 16, 0, 0);
        }
        char* al = (char*)(&Alds[sbuf][0][0][0]);
        for (int idx = w; idx < NI * 4; idx += 4) {
            int p = idx & 1, c = idx >> 1;
            int row = c * 16 + (lane >> 2);
            int ss = (lane & 3) ^ ((row >> 1) & 3);
            int mrow = m0 + row;
            if (mrow > M - 1) mrow = M - 1;
            const __bf16* ap = (p ? Apl : Aph) + (size_t)mrow * Krow + kt * 32 + ss * 8;
            __builtin_amdgcn_global_load_lds((const unsigned int*)ap,
                (unsigned int*)(al + p * (NI * 2048) + (c << 10)), 16, 0, 0);
        }
    };

    f32x4 acc[NI][4];
#pragma unroll
    for (int i = 0; i < NI; ++i)
#pragma unroll
        for (int j = 0; j < 4; ++j)
#pragma unroll
            for (int r = 0; r < 4; ++r) acc[i][j][r] = 0.0f;

    stage(0, 0);
    __syncthreads();
    for (int kt = 0; kt < KT; ++kt) {
        int buf = kt & 1;
        if (kt + 1 < KT) stage(buf ^ 1, kt + 1);   // prefetch: drained by barrier
        bf16x8 afh[NI], afl[NI], bh[4], bl4[4];
        const char* ab = (const char*)(&Alds[buf][0][0][0]);
#pragma unroll
        for (int i = 0; i < NI; ++i) {
            int row = wm + i * 16 + lr;
            int off = (q * 16) ^ (((row >> 1) & 3) << 4);
            afh[i] = *(const bf16x8*)(ab + row * 64 + off);
            afl[i] = *(const bf16x8*)(ab + NI * 2048 + row * 64 + off);
        }
        const char* bb = (const char*)(&Blds[buf][0][0][0][0]);
#pragma unroll
        for (int j = 0; j < 4; ++j) {
            int bsub, brow;
            if constexpr (MODE == M_GLU) {
                bsub = j >> 1;
                brow = (w & 1) * 32 + (j & 1) * 16 + lr;
            } else {
                bsub = w & 1;
                brow = j * 16 + lr;
            }
            int off = (q * 16) ^ (((brow >> 1) & 3) << 4);
            bh[j] = *(const bf16x8*)(bb + bsub * 8192 + brow * 64 + off);
            bl4[j] = *(const bf16x8*)(bb + bsub * 8192 + 4096 + brow * 64 + off);
        }
#pragma unroll
        for (int i = 0; i < NI; ++i)
#pragma unroll
            for (int j = 0; j < 4; ++j) {
                MFMA3(acc[i][j], afh[i], afl[i], bh[j], bl4[j]);
            }
        __syncthreads();
    }

    if constexpr (MODE == M_QKV) {
        int sel = nb >> 2;
        int c0 = (nb & 3) * 128 + (w & 1) * 64;
        if (sel == 2) {
            // V^T hi/lo planes: Vt[(n)][token], 8B vector stores over r
#pragma unroll
            for (int i = 0; i < NI; ++i) {
                int mb2 = m0 + wm + i * 16 + q * 4;
#pragma unroll
                for (int j = 0; j < 4; ++j) {
                    int n = c0 + j * 16 + lr;
                    bf16x4 h4, l4;
#pragma unroll
                    for (int r = 0; r < 4; ++r) {
                        float v = acc[i][j][r] + b2[n];
                        __bf16 hh = (__bf16)v;
                        h4[r] = hh;
                        l4[r] = (__bf16)(v - (float)hh);
                    }
                    if (mb2 + 3 < M) {
                        *(bf16x4*)(O3h + (size_t)n * LTP + mb2) = h4;
                        *(bf16x4*)(O3l + (size_t)n * LTP + mb2) = l4;
                    } else {
#pragma unroll
                        for (int r = 0; r < 4; ++r)
                            if (mb2 + r < M) {
                                O3h[(size_t)n * LTP + mb2 + r] = h4[r];
                                O3l[(size_t)n * LTP + mb2 + r] = l4[r];
                            }
                    }
                }
            }
        } else {
            const float* bias = sel == 0 ? b0 : b1;
            __bf16* Dh = sel == 0 ? Oh : O2h;
            __bf16* Dl = sel == 0 ? Ol : O2l;
            float scale = sel == 0 ? 0.125f : 1.0f;   // fold softmax scale into Q
#pragma unroll
            for (int i = 0; i < NI; ++i)
#pragma unroll
                for (int r = 0; r < 4; ++r) {
                    int m = m0 + wm + i * 16 + q * 4 + r;
                    if (m >= M) continue;
#pragma unroll
                    for (int j = 0; j < 4; ++j) {
                        int n = c0 + j * 16 + lr;
                        float v = (acc[i][j][r] + bias[n]) * scale;
                        __bf16 hh = (__bf16)v;
                        Dh[(size_t)m * DM + n] = hh;
                        Dl[(size_t)m * DM + n] = (__bf16)(v - (float)hh);
                    }
                }
        }
        return;
    }

#pragma unroll
    for (int i = 0; i < NI; ++i)
#pragma unroll
        for (int r = 0; r < 4; ++r) {
            int m = m0 + wm + i * 16 + q * 4 + r;
            if (m >= M) continue;
            if constexpr (MODE == M_GATE1) {
                int r6 = (m < LZ) ? (m / SEQ) : 6;
                const float* g1 = params + r6 * 3072 + 2048;
                int c0 = nb * 128 + (w & 1) * 64;
#pragma unroll
                for (int j = 0; j < 4; ++j) {
                    int n = c0 + j * 16 + lr;
                    size_t o = (size_t)m * 512 + n;
                    float x = (float)Xh[o] + (float)Xl[o];
                    float v = x * g1[n] + acc[i][j][r] + b0[n];
                    __bf16 hh = (__bf16)v;
                    Oh[o] = hh;
                    Ol[o] = (__bf16)(v - (float)hh);
                }
            } else if constexpr (MODE == M_GLU) {
#pragma unroll
                for (int j = 0; j < 2; ++j) {
                    int n = nb * 64 + (w & 1) * 32 + j * 16 + lr;
                    float a = acc[i][j][r] + b0[n];
                    float g = acc[i][j + 2][r] + b0[2048 + n];
                    float gel = 0.5f * g * (1.0f + erff(g * 0.70710678118654752f));
                    float v = a * gel;
                    size_t o = (size_t)m * 2048 + n;
                    __bf16 hh = (__bf16)v;
                    Oh[o] = hh;
                    Ol[o] = (__bf16)(v - (float)hh);
                }
            } else {
                int r6 = (m < LZ) ? (m / SEQ) : 6;
                const float* g2 = params + r6 * 3072 + 2560;
                int c0 = nb * 128 + (w & 1) * 64;
#pragma unroll
                for (int j = 0; j < 4; ++j) {
                    int n = c0 + j * 16 + lr;
                    C0[(size_t)m * 512 + n] = (acc[i][j][r] + b0[n]) * g2[n];
                }
            }
        }
}

// ---- flash attention: all operands pre-split bf16 planes -------------------
__global__ __launch_bounds__(256) void fattn_kernel(
    const __bf16* __restrict__ Qph, const __bf16* __restrict__ Qpl,
    const __bf16* __restrict__ Kph, const __bf16* __restrict__ Kpl,
    const __bf16* __restrict__ Vph, const __bf16* __restrict__ Vpl,
    __bf16* __restrict__ Oh, __bf16* __restrict__ Ol) {
    __shared__ __align__(16) __bf16 Ksh[2][64][64];
    __shared__ __align__(16) __bf16 Vsh[2][64][64];
    __shared__ __align__(16) __bf16 Ph[4][16][72], Pl[4][16][72];
    int tid = threadIdx.x;
    int w = tid >> 6, lane = tid & 63;
    int lq = lane & 15, lg = lane >> 4;
    int hoff = blockIdx.z * DH;
    int qbase, base0, len0, base1, len1;
    if (blockIdx.y < 6) {
        int f = blockIdx.y;
        qbase = f * SEQ;
        base0 = f * SEQ; len0 = SEQ;
        int jl = f - 4; if (jl < 0) jl = 0;
        base1 = LZ + jl * SEQ; len1 = (f - jl) * SEQ;
    } else {
        int f = blockIdx.y - 6;
        qbase = LZ + f * SEQ;
        base0 = LZ; len0 = (f + 1) * SEQ;
        base1 = 0; len1 = 0;
    }
    int q0 = blockIdx.x * 64;
    int qvalid = SEQ - q0; if (qvalid > 64) qvalid = 64;

    bf16x8 qfh[2], qfl[2];
    {
        int qr = w * 16 + lq;
        int tok = qbase + q0 + ((qr < qvalid) ? qr : 0);
        const __bf16* qph = Qph + (size_t)tok * DM + hoff + lg * 8;
        const __bf16* qpl = Qpl + (size_t)tok * DM + hoff + lg * 8;
#pragma unroll
        for (int s = 0; s < 2; ++s) {
            qfh[s] = *(const bf16x8*)(qph + s * 32);
            qfl[s] = *(const bf16x8*)(qpl + s * 32);
        }
    }
    f32x4 acc[4];
#pragma unroll
    for (int n = 0; n < 4; ++n)
#pragma unroll
        for (int r = 0; r < 4; ++r) acc[n][r] = 0.0f;
    float m_i = -1e30f, l_i = 0.0f;
    int slot = lane & 7, rsub = lane >> 3;

    for (int rng = 0; rng < 2; ++rng) {
        int base = rng ? base1 : base0;
        int len = rng ? len1 : len0;
        if (len == 0) continue;
        int tend = base + len;
        for (int t = base & ~63; t < tend; t += 64) {
            int lo = base - t; if (lo < 0) lo = 0;
            int hi = tend - t; if (hi > 64) hi = 64;
            __syncthreads();
#pragma unroll
            for (int ii = 0; ii < 4; ++ii) {
                int idx = w + ii * 4;
                int p = idx >> 3, c = idx & 7;
                int row = c * 8 + rsub;
                const __bf16* g = (p ? Kpl : Kph) +
                    (size_t)(t + row) * DM + hoff + (slot ^ (row & 7)) * 8;
                __builtin_amdgcn_global_load_lds((const unsigned int*)g,
                    (unsigned int*)((char*)(&Ksh[p][0][0]) + c * 1024), 16, 0, 0);
            }
#pragma unroll
            for (int ii = 0; ii < 4; ++ii) {
                int idx = w + ii * 4;
                int p = idx >> 3, c = idx & 7;
                int d = c * 8 + rsub;
                const __bf16* g = (p ? Vpl : Vph) +
                    (size_t)(hoff + d) * LTP + t + (slot ^ (d & 7)) * 8;
                __builtin_amdgcn_global_load_lds((const unsigned int*)g,
                    (unsigned int*)((char*)(&Vsh[p][0][0]) + c * 1024), 16, 0, 0);
            }
            __syncthreads();
            f32x4 st[4];
#pragma unroll
            for (int sub = 0; sub < 4; ++sub)
#pragma unroll
                for (int r = 0; r < 4; ++r) st[sub][r] = 0.0f;
#pragma unroll
            for (int sub = 0; sub < 4; ++sub) {
                int row = sub * 16 + lq;
#pragma unroll
                for (int s = 0; s < 2; ++s) {
                    int sl = ((s * 4 + lg) ^ (row & 7)) * 8;
                    bf16x8 kfh = *(const bf16x8*)(&Ksh[0][row][sl]);
                    bf16x8 kfl = *(const bf16x8*)(&Ksh[1][row][sl]);
                    MFMA3(st[sub], kfh, kfl, qfh[s], qfl[s]);
                }
            }
            float p[16];
            float rmax = -1e30f;
#pragma unroll
            for (int sub = 0; sub < 4; ++sub)
#pragma unroll
                for (int r = 0; r < 4; ++r) {
                    int kk = sub * 16 + lg * 4 + r;
                    float sv = (kk >= lo && kk < hi) ? st[sub][r] : -1e30f;
                    p[sub * 4 + r] = sv;
                    rmax = fmaxf(rmax, sv);
                }
            rmax = fmaxf(rmax, __shfl_xor(rmax, 16));
            rmax = fmaxf(rmax, __shfl_xor(rmax, 32));
            float mnew = fmaxf(m_i, rmax);
            float alpha = __expf(m_i - mnew);
            float rsum = 0.0f;
#pragma unroll
            for (int i2 = 0; i2 < 16; ++i2) {
                p[i2] = __expf(p[i2] - mnew);
                rsum += p[i2];
            }
            rsum += __shfl_xor(rsum, 16);
            rsum += __shfl_xor(rsum, 32);
            l_i = l_i * alpha + rsum;
            m_i = mnew;
            float ar[4];
#pragma unroll
            for (int r = 0; r < 4; ++r) ar[r] = __shfl(alpha, lg * 4 + r);
#pragma unroll
            for (int n = 0; n < 4; ++n)
#pragma unroll
                for (int r = 0; r < 4; ++r) acc[n][r] *= ar[r];
#pragma unroll
            for (int sub = 0; sub < 4; ++sub) {
                bf16x4 h4, l4;
#pragma unroll
                for (int r = 0; r < 4; ++r) {
                    float x = p[sub * 4 + r];
                    __bf16 hh = (__bf16)x;
                    h4[r] = hh;
                    l4[r] = (__bf16)(x - (float)hh);
                }
                *(bf16x4*)&Ph[w][lq][sub * 16 + lg * 4] = h4;
                *(bf16x4*)&Pl[w][lq][sub * 16 + lg * 4] = l4;
            }
            bf16x8 pah[2], pal[2];
#pragma unroll
            for (int s = 0; s < 2; ++s) {
                pah[s] = *(const bf16x8*)(&Ph[w][lq][s * 32 + lg * 8]);
                pal[s] = *(const bf16x8*)(&Pl[w][lq][s * 32 + lg * 8]);
            }
#pragma unroll
            for (int n = 0; n < 4; ++n) {
                int row = n * 16 + lq;
#pragma unroll
                for (int s = 0; s < 2; ++s) {
                    int sl = ((s * 4 + lg) ^ (row & 7)) * 8;
                    bf16x8 vfh = *(const bf16x8*)(&Vsh[0][row][sl]);
                    bf16x8 vfl = *(const bf16x8*)(&Vsh[1][row][sl]);
                    MFMA3(acc[n], pah[s], pal[s], vfh, vfl);
                }
            }
        }
    }
    float linv[4];
#pragma unroll
    for (int r = 0; r < 4; ++r) linv[r] = 1.0f / __shfl(l_i, lg * 4 + r);
#pragma unroll
    for (int r = 0; r < 4; ++r) {
        int qr = w * 16 + lg * 4 + r;
        if (qr < qvalid) {
            size_t ob = (size_t)(qbase + q0 + qr) * DM + hoff;
#pragma unroll
            for (int n = 0; n < 4; ++n) {
                float v = acc[n][r] * linv[r];
                __bf16 hh = (__bf16)v;
                Oh[ob + n * 16 + lq] = hh;
                Ol[ob + n * 16 + lq] = (__bf16)(v - (float)hh);
            }
        }
    }
}

// ---------------- unpatch to FP32 output ------------------
// Same serial-latency fix: 4 accumulators + unroll-8 (stride-12 column dot).
__global__ void unpatch_kernel(const float* __restrict__ state,
                               const float* __restrict__ Wu,
                               const float* __restrict__ bu,
                               float* __restrict__ out) {
    int idx = blockIdx.x * blockDim.x + threadIdx.x;
    if (idx >= DURZ * 3 * 32 * 32) return;
    int w = idx & 31, hh = (idx >> 5) & 31, c = (idx >> 10) % 3, f = idx / (3 * 1024);
    int t = (hh >> 1) * 16 + (w >> 1);
    int j = c * 4 + (hh & 1) * 2 + (w & 1);
    const float* xr = state + (size_t)(f * SEQ + t) * DM;
    const float* wu = Wu + j;
    float a0 = 0.0f, a1 = 0.0f, a2 = 0.0f, a3 = 0.0f;
#pragma unroll 8
    for (int k = 0; k < DM; k += 4) {
        a0 = fmaf(xr[k + 0], wu[(k + 0) * 12], a0);
        a1 = fmaf(xr[k + 1], wu[(k + 1) * 12], a1);
        a2 = fmaf(xr[k + 2], wu[(k + 2) * 12], a2);
        a3 = fmaf(xr[k + 3], wu[(k + 3) * 12], a3);
    }
    out[idx] = bu[j] + (a0 + a1) + (a2 + a3);
}

extern "C" void kernel_launch(void* const* d_in, const int* in_sizes, int n_in,
                              void* d_out, int out_size, void* d_ws, size_t ws_size,
                              hipStream_t stream) {
    static const int expected_sizes[32] = {
        18432, 15360, 6, 6,
        6144, 512, 6144, 12,
        512, 131072, 1536, 512000,
        3145728, 6144, 3145728, 6144,
        1572864, 3072, 1572864, 3072,
        1572864, 3072, 1572864, 3072,
        1572864, 3072, 1572864, 3072,
        12582912, 24576, 6291456, 3072
    };
    if (n_in != 32) {
        fill_kernel<<<(18432 + 255) / 256, 256, 0, stream>>>((float*)d_out, 18432, 3.0f);
        return;
    }
    for (int i = 0; i < 32; ++i) {
        if (in_sizes[i] != expected_sizes[i]) {
            fill_kernel<<<(18432 + 255) / 256, 256, 0, stream>>>((float*)d_out, 18432,
                                                                 4.0f + (float)i);
            return;
        }
    }

    const float* z = (const float*)d_in[0];
    const float* frames = (const float*)d_in[1];
    const int* actions = (const int*)d_in[2];
    const int* ts = (const int*)d_in[3];
    const float* W_patch = (const float*)d_in[4];
    const float* b_patch = (const float*)d_in[5];
    const float* W_unpatch = (const float*)d_in[6];
    const float* b_unpatch = (const float*)d_in[7];
    const float* registers = (const float*)d_in[8];
    const float* pe_grid = (const float*)d_in[9];
    const float* action_emb = (const float*)d_in[10];
    const float* time_emb = (const float*)d_in[11];
    const float* W_mod1 = (const float*)d_in[12];
    const float* b_mod1 = (const float*)d_in[13];
    const float* W_mod2 = (const float*)d_in[14];
    const float* b_mod2 = (const float*)d_in[15];
    const float* W_q = (const float*)d_in[16];
    const float* b_q = (const float*)d_in[17];
    const float* W_k = (const float*)d_in[18];
    const float* b_k = (const float*)d_in[19];
    const float* W_v = (const float*)d_in[20];
    const float* b_v = (const float*)d_in[21];
    const float* W_o = (const float*)d_in[22];
    const float* b_o = (const float*)d_in[23];
    const float* W_g1 = (const float*)d_in[24];
    const float* b_g1 = (const float*)d_in[25];
    const float* W_g2 = (const float*)d_in[26];
    const float* b_g2 = (const float*)d_in[27];
    const float* W_geglu = (const float*)d_in[28];
    const float* b_geglu = (const float*)d_in[29];
    const float* W_ffout = (const float*)d_in[30];
    const float* b_ffout = (const float*)d_in[31];

    const size_t S = (size_t)LT * DM;          // 1,447,424 floats
    const size_t PLE = (size_t)LTP * DM;       // plane bf16 elems = 1,474,560
    const size_t PLF = PLE / 2;                // plane floats = 737,280
    size_t need = (4 * S + 6 * PLF + 129024 + 7168 + 4194304) * sizeof(float);
    if (ws_size < need) {
        fill_kernel<<<(18432 + 255) / 256, 256, 0, stream>>>((float*)d_out, 18432, 40.0f);
        return;
    }
    float* ws = (float*)d_ws;
    float* state = ws;                              // [0, 1S)
    __bf16* xnh = (__bf16*)(ws + S);                // [1S, 1.5S)
    __bf16* xnl = (__bf16*)(ws + S + S / 2);        // [1.5S, 2S)
    __bf16* Qh = (__bf16*)(ws + 2 * S);             // 6 planes of PLE bf16
    __bf16* Ql = Qh + PLE;
    __bf16* Kh = Qh + 2 * PLE;
    __bf16* Kl = Qh + 3 * PLE;
    __bf16* Vth = Qh + 4 * PLE;
    __bf16* Vtl = Qh + 5 * PLE;
    float* aoff = ws + 2 * S + 6 * PLF;
    __bf16* atth = (__bf16*)aoff;                   // S bf16
    __bf16* attl = atth + S;
    __bf16* y2h = (__bf16*)(aoff + S);
    __bf16* y2l = y2h + S;
    __bf16* Hph = (__bf16*)(ws + 2 * S);            // overlay (planes+att dead)
    __bf16* Hpl = Hph + (size_t)LT * HIDDEN;
    float* params = aoff + 2 * S;
    float* condraw = params + 129024;
    float* condsilu = condraw + 3584;
    float* wp = condsilu + 3584;                    // 4,194,304 floats

    embed_kernel<<<LT, 256, 0, stream>>>(z, frames, actions, W_patch, b_patch,
                                         registers, pe_grid, action_emb, state);
    cond_kernel<<<(7 * 512 + 255) / 256, 256, 0, stream>>>(ts, time_emb, condraw, condsilu);
    params_kernel<<<504, 256, 0, stream>>>(
        condraw, condsilu, W_mod1, b_mod1, W_mod2, b_mod2, W_g1, b_g1, W_g2, b_g2, params);
    ztail_kernel<<<((LTP - LT) * 512 + 255) / 256, 256, 0, stream>>>(Kh, Kl, Vth, Vtl);

    dim3 gqkv(45, 12);
    dim3 ggate1(45, 4);
    dim3 gglu(23, 32);
    dim3 ggate2(45, 4);
    dim3 gattn(5, 11, NHEADS);
    for (int i = 0; i < 6; ++i) {
        const float* P = params + i * 21504;
        wprep_kernel<<<2048, 256, 0, stream>>>(
            W_q + (size_t)i * DM * DM, W_k + (size_t)i * DM * DM,
            W_v + (size_t)i * DM * DM, W_o + (size_t)i * DM * DM,
            W_geglu + (size_t)i * DM * 4096, W_ffout + (size_t)i * HIDDEN * DM, wp);
        lnmod_kernel<false><<<LT, 256, 0, stream>>>(state, nullptr, nullptr,
                                                    xnh, xnl, P, 0);
        gemm_kernel<M_QKV, 2><<<gqkv, 256, 0, stream>>>(
            xnh, xnl, (const char*)wp, 16, 512,
            b_q + i * DM, b_k + i * DM, b_v + i * DM, nullptr,
            Qh, Ql, Kh, Kl, Vth, Vtl, nullptr, nullptr, nullptr, LT);
        fattn_kernel<<<gattn, 256, 0, stream>>>(Qh, Ql, Kh, Kl, Vth, Vtl, atth, attl);
        gemm_kernel<M_GATE1, 2><<<ggate1, 256, 0, stream>>>(
            atth, attl, (const char*)(wp + 786432), 16, 512,
            b_o + i * DM, nullptr, nullptr, nullptr,
            y2h, y2l, nullptr, nullptr, nullptr, nullptr, xnh, xnl, P, LT);
        lnmod_kernel<true><<<LT, 256, 0, stream>>>(nullptr, y2h, y2l,
                                                   xnh, xnl, P, 1024);
        gemm_kernel<M_GLU, 4><<<gglu, 256, 0, stream>>>(
            xnh, xnl, (const char*)(wp + 1048576), 16, 512,
            b_geglu + (size_t)i * 4096, nullptr, nullptr, nullptr,
            Hph, Hpl, nullptr, nullptr, nullptr, nullptr, nullptr, nullptr, nullptr, LT);
        gemm_kernel<M_GATE2, 2><<<ggate2, 256, 0, stream>>>(
            Hph, Hpl, (const char*)(wp + 3145728), 64, 2048,
            b_ffout + i * DM, nullptr, nullptr, state,
            nullptr, nullptr, nullptr, nullptr, nullptr, nullptr,
            nullptr, nullptr, P, LT);
    }
    unpatch_kernel<<<(DURZ * 3 * 32 * 32 + 255) / 256, 256, 0, stream>>>(
        state, W_unpatch, b_unpatch, (float*)d_out);
}